// Round 8
// baseline (567.274 us; speedup 1.0000x reference)
//
#include <hip/hip_runtime.h>
#include <math.h>

#define BB 4
#define NN 512
#define DIMX 384
#define HH 8
#define PDD 64
#define JC 64
#define PWPAD 65   // odd pad: scalar row-read bank (l+d)%32 and column-read bank (j+l)%32 both 2-way (free, m136)

static constexpr float EPSV = 1e-8f;
static constexpr float SCALAR_SCALE = 0.14433756729740643f;  // (3*16)^-0.5
static constexpr float POINT_SCALE  = 0.1360827634879543f;   // (3*4*4.5)^-0.5
static constexpr float PAIR_SCALE   = 0.5773502691896258f;   // 3^-0.5

// ---------------- rope table ----------------
__global__ void k_rope(float* __restrict__ cos_t, float* __restrict__ sin_t) {
    int n = blockIdx.x * blockDim.x + threadIdx.x;
    if (n >= NN) return;
#pragma unroll
    for (int i = 0; i < 8; ++i) {
        float invf = powf(10000.0f, -(float)i / 8.0f);
        float f = (float)n * invf;
        cos_t[n * 8 + i] = cosf(f);
        sin_t[n * 8 + i] = sinf(f);
    }
}

// ---------------- projections + transforms (column-half split) ----------------
// K/V stored d-major, float4-packed per j: ks/vs [bh][4][N]f4, kp [bh][3][N]f4, vp [bh][6][N]f4.
__global__ __launch_bounds__(256) void k_proj(
    const float* __restrict__ x, const float* __restrict__ rot,
    const float* __restrict__ trans, const int* __restrict__ pos_ids,
    const float* __restrict__ Wq_s, const float* __restrict__ Wk_s, const float* __restrict__ Wv_s,
    const float* __restrict__ Wq_p, const float* __restrict__ Wk_p, const float* __restrict__ Wv_p,
    const float* __restrict__ cos_t, const float* __restrict__ sin_t,
    float* __restrict__ qsg, float* __restrict__ qpg, float* __restrict__ qqg,
    float4* __restrict__ kst, float* __restrict__ kpt, float* __restrict__ kkg,
    float4* __restrict__ vst, float* __restrict__ vpt)
{
    __shared__ float xl[8][DIMX];
    __shared__ float raw[8][384];
    const int t = threadIdx.x;
    const int tile = blockIdx.x >> 1;
    const int half = blockIdx.x & 1;
    const int tok0 = tile * 8;

    {
        const float4* xg = (const float4*)(x + (size_t)tok0 * DIMX);
        float4* xl4 = (float4*)&xl[0][0];
#pragma unroll
        for (int k = 0; k < 3; ++k) xl4[t + 256 * k] = xg[t + 256 * k];
    }
    __syncthreads();

    const int tok = t >> 5, l = t & 31;
    {
        float4 acc[3];
        const float* wb[3];
        int st[3];
#pragma unroll
        for (int m = 0; m < 3; ++m) {
            int f = l + 32 * m + 96 * half;
            const float* w; int out, c;
            if (f < 32)       { w = Wq_s; out = 128; c = 4 * f; }
            else if (f < 64)  { w = Wk_s; out = 128; c = 4 * f - 128; }
            else if (f < 96)  { w = Wv_s; out = 128; c = 4 * f - 256; }
            else if (f < 120) { w = Wq_p; out = 96;  c = 4 * f - 384; }
            else if (f < 144) { w = Wk_p; out = 96;  c = 4 * f - 480; }
            else              { w = Wv_p; out = 192; c = 4 * f - 576; }
            wb[m] = w + c; st[m] = out;
            acc[m] = make_float4(0.f, 0.f, 0.f, 0.f);
        }
        for (int dd = 0; dd < DIMX; ++dd) {
            float xv = xl[tok][dd];
#pragma unroll
            for (int m = 0; m < 3; ++m) {
                float4 wv = *(const float4*)(wb[m] + (size_t)dd * st[m]);
                acc[m].x = fmaf(xv, wv.x, acc[m].x);
                acc[m].y = fmaf(xv, wv.y, acc[m].y);
                acc[m].z = fmaf(xv, wv.z, acc[m].z);
                acc[m].w = fmaf(xv, wv.w, acc[m].w);
            }
        }
#pragma unroll
        for (int m = 0; m < 3; ++m)
            *(float4*)&raw[tok][4 * (l + 32 * m)] = acc[m];
    }
    __syncthreads();

    const int h = l >> 2, q = l & 3;
    const int n_g = tok0 + tok;
    const int b = n_g / NN;
    const int nloc = n_g - b * NN;
    const int bh = b * HH + h;
    const size_t rowi = (size_t)bh * NN + nloc;

    if (half == 0) {
        const int pos = pos_ids[n_g];
        float qv[4], kv[4], vv[4];
#pragma unroll
        for (int dd0 = 0; dd0 < 4; ++dd0) {
            int dd = q * 4 + dd0;
            int i8 = dd & 7;
            float c = cos_t[pos * 8 + i8], s = sin_t[pos * 8 + i8];
            float xq = raw[tok][h * 16 + dd];
            float rq = (dd < 8) ? -raw[tok][h * 16 + dd + 8] : raw[tok][h * 16 + dd - 8];
            qv[dd0] = fmaf(xq, c, rq * s);
            float xk = raw[tok][128 + h * 16 + dd];
            float rk = (dd < 8) ? -raw[tok][128 + h * 16 + dd + 8] : raw[tok][128 + h * 16 + dd - 8];
            kv[dd0] = fmaf(xk, c, rk * s);
            vv[dd0] = raw[tok][256 + h * 16 + dd];
        }
        *(float4*)&qsg[rowi * 16 + q * 4] = make_float4(qv[0], qv[1], qv[2], qv[3]);
        kst[(size_t)bh * 2048 + q * 512 + nloc] = make_float4(kv[0], kv[1], kv[2], kv[3]);
        vst[(size_t)bh * 2048 + q * 512 + nloc] = make_float4(vv[0], vv[1], vv[2], vv[3]);
    } else {
        const float* Rm = rot + (size_t)n_g * 9;
        const float trv[3] = {trans[n_g * 3 + 0], trans[n_g * 3 + 1], trans[n_g * 3 + 2]};
        float qqp = 0.f, kkp = 0.f;
        {
            float pc[3], kc[3];
#pragma unroll
            for (int c = 0; c < 3; ++c) {
                pc[c] = raw[tok][h * 12 + q * 3 + c];
                kc[c] = raw[tok][96 + h * 12 + q * 3 + c];
            }
#pragma unroll
            for (int r = 0; r < 3; ++r) {
                float vq = trv[r], vk = trv[r];
#pragma unroll
                for (int c = 0; c < 3; ++c) {
                    vq = fmaf(pc[c], Rm[c * 3 + r], vq);
                    vk = fmaf(kc[c], Rm[c * 3 + r], vk);
                }
                qpg[rowi * 12 + q * 3 + r] = vq;
                int d = q * 3 + r;   // 0..11
                kpt[(size_t)bh * 6144 + (d >> 2) * 2048 + nloc * 4 + (d & 3)] = vk;
                qqp = fmaf(vq, vq, qqp);
                kkp = fmaf(vk, vk, kkp);
            }
        }
        qqp += __shfl_xor(qqp, 1); qqp += __shfl_xor(qqp, 2);
        kkp += __shfl_xor(kkp, 1); kkp += __shfl_xor(kkp, 2);
        if (q == 0) { qqg[rowi] = qqp; kkg[rowi] = kkp; }
#pragma unroll
        for (int pp = 0; pp < 2; ++pp) {
            int p = q + 4 * pp;
            float pc[3];
#pragma unroll
            for (int c = 0; c < 3; ++c) pc[c] = raw[tok][192 + h * 24 + p * 3 + c];
#pragma unroll
            for (int r = 0; r < 3; ++r) {
                float v = trv[r];
#pragma unroll
                for (int c = 0; c < 3; ++c) v = fmaf(pc[c], Rm[c * 3 + r], v);
                int d = p * 3 + r;   // 0..23
                vpt[(size_t)bh * 12288 + (d >> 2) * 2048 + nloc * 4 + (d & 3)] = v;
            }
        }
    }
}

// ---------------- fused attention: 512 threads, wave = head, lane = j ----------------
// pw tile [64][65] scalar access (r5 proven pattern, 2-way banks everywhere).
// (512,4): 2 blocks/CU resident (VGPR cap 128 >= 88 used) -> cross-block latency hiding.
__global__ __launch_bounds__(512, 4) void k_attn(
    const float* __restrict__ pairw,
    const float* __restrict__ rot, const float* __restrict__ trans,
    const float* __restrict__ Wpair, const float* __restrict__ bpair,
    const float* __restrict__ pweights,
    const float* __restrict__ qsg, const float* __restrict__ qpg, const float* __restrict__ qqg,
    const float4* __restrict__ kst, const float4* __restrict__ kpt, const float* __restrict__ kkg,
    const float4* __restrict__ vst, const float4* __restrict__ vpt,
    float* __restrict__ feats)
{
    __shared__ float pwt[2][JC][PWPAD]; // double-buffered padded tile
    __shared__ float Wp_t[HH][64];      // W_pair transposed [h][d]
    __shared__ float plds[HH][JC];      // per-head probs (same-wave write->read)
    __shared__ float qsh[HH][16];
    __shared__ float qph[HH][12];
    __shared__ float qqh[HH];

    const int t = threadIdx.x;
    const int bi = blockIdx.x;
    const int b = bi >> 9;
    const int h = t >> 6, l = t & 63;  // wave = head, lane = j-in-chunk

    { int d = t >> 3, hh = t & 7; Wp_t[hh][d] = Wpair[t]; }

    const int bh = b * HH + h;
    const size_t rowq = (size_t)bh * NN + (bi & 511);
    if (l < 16) qsh[h][l] = qsg[rowq * 16 + l];
    if (l < 12) qph[h][l] = qpg[rowq * 12 + l];
    if (l == 0) qqh[h] = qqg[rowq];

    const float coefP = -0.5f * log1pf(__expf(pweights[h])) * POINT_SCALE;
    const float bp_h = bpair[h];

    const float4* ksb = kst + (size_t)bh * 2048;   // [4][512] f4
    const float4* vsb = vst + (size_t)bh * 2048;   // [4][512] f4
    const float4* kpb = kpt + (size_t)bh * 1536;   // [3][512] f4
    const float4* vpb = vpt + (size_t)bh * 3072;   // [6][512] f4
    const float*  kkb = kkg + (size_t)bh * 512;

    const float4* pwsrc = (const float4*)(pairw + (size_t)bi * NN * PDD);

    // prologue: stage chunk 0 into pwt[0] (scalar stores, pad-65)
    {
        float4 vA = pwsrc[t], vB = pwsrc[t + 512];
        int jA = t >> 4, dA = (t & 15) * 4;
        pwt[0][jA][dA] = vA.x; pwt[0][jA][dA + 1] = vA.y; pwt[0][jA][dA + 2] = vA.z; pwt[0][jA][dA + 3] = vA.w;
        int f2 = t + 512, jB = f2 >> 4, dB = (f2 & 15) * 4;
        pwt[0][jB][dB] = vB.x; pwt[0][jB][dB + 1] = vB.y; pwt[0][jB][dB + 2] = vB.z; pwt[0][jB][dB + 3] = vB.w;
    }
    __syncthreads();

    float m = -3.0e38f, lsum = 0.f;
    float ap0 = 0.f, ap1 = 0.f, ap2 = 0.f, ap3 = 0.f;
    float ascd[16], aptd[24];
#pragma unroll
    for (int d = 0; d < 16; ++d) ascd[d] = 0.f;
#pragma unroll
    for (int d = 0; d < 24; ++d) aptd[d] = 0.f;

    for (int c = 0; c < NN / JC; ++c) {
        const int cur = c & 1, nxt = cur ^ 1;
        float4 nA, nB;
        const bool more = (c < NN / JC - 1);
        if (more) {
            const float4* s = pwsrc + (size_t)(c + 1) * 1024;
            nA = s[t]; nB = s[t + 512];
        }
        const float (*pwc)[PWPAD] = pwt[cur];
        // ---- pair bias for my j: 64 scalar reads (2-way banks, free), 4 fma chains ----
        float b0 = 0.f, b1 = 0.f, b2 = 0.f, b3 = 0.f;
#pragma unroll
        for (int d = 0; d < 64; d += 4) {
            b0 = fmaf(pwc[l][d + 0], Wp_t[h][d + 0], b0);
            b1 = fmaf(pwc[l][d + 1], Wp_t[h][d + 1], b1);
            b2 = fmaf(pwc[l][d + 2], Wp_t[h][d + 2], b2);
            b3 = fmaf(pwc[l][d + 3], Wp_t[h][d + 3], b3);
        }
        const float bias = ((b0 + b1) + (b2 + b3) + bp_h) * PAIR_SCALE;
        // ---- logit (f4-packed d-major loads, all stride-1 coalesced) ----
        const int j = c * JC + l;
        float lg;
        {
            const float4 qs0 = *(const float4*)&qsh[h][0];
            const float4 qs1 = *(const float4*)&qsh[h][4];
            const float4 qs2 = *(const float4*)&qsh[h][8];
            const float4 qs3 = *(const float4*)&qsh[h][12];
            float4 k0 = ksb[j], k1 = ksb[512 + j], k2 = ksb[1024 + j], k3 = ksb[1536 + j];
            float d0 = 0.f, d1 = 0.f;
            d0 = fmaf(qs0.x, k0.x, d0); d0 = fmaf(qs0.y, k0.y, d0);
            d0 = fmaf(qs0.z, k0.z, d0); d0 = fmaf(qs0.w, k0.w, d0);
            d1 = fmaf(qs1.x, k1.x, d1); d1 = fmaf(qs1.y, k1.y, d1);
            d1 = fmaf(qs1.z, k1.z, d1); d1 = fmaf(qs1.w, k1.w, d1);
            d0 = fmaf(qs2.x, k2.x, d0); d0 = fmaf(qs2.y, k2.y, d0);
            d0 = fmaf(qs2.z, k2.z, d0); d0 = fmaf(qs2.w, k2.w, d0);
            d1 = fmaf(qs3.x, k3.x, d1); d1 = fmaf(qs3.y, k3.y, d1);
            d1 = fmaf(qs3.z, k3.z, d1); d1 = fmaf(qs3.w, k3.w, d1);
            const float4 qp0 = *(const float4*)&qph[h][0];
            const float4 qp1 = *(const float4*)&qph[h][4];
            const float4 qp2 = *(const float4*)&qph[h][8];
            float4 P0 = kpb[j], P1 = kpb[512 + j], P2 = kpb[1024 + j];
            float e0 = 0.f, e1 = 0.f;
            e0 = fmaf(qp0.x, P0.x, e0); e0 = fmaf(qp0.y, P0.y, e0);
            e0 = fmaf(qp0.z, P0.z, e0); e0 = fmaf(qp0.w, P0.w, e0);
            e1 = fmaf(qp1.x, P1.x, e1); e1 = fmaf(qp1.y, P1.y, e1);
            e1 = fmaf(qp1.z, P1.z, e1); e1 = fmaf(qp1.w, P1.w, e1);
            e0 = fmaf(qp2.x, P2.x, e0); e0 = fmaf(qp2.y, P2.y, e0);
            e0 = fmaf(qp2.z, P2.z, e0); e0 = fmaf(qp2.w, P2.w, e0);
            float dist = qqh[h] + kkb[j] - 2.f * (e0 + e1);
            lg = fmaf(d0 + d1, SCALAR_SCALE, fmaf(coefP, dist, bias));
        }
        // ---- online softmax across the 64-lane wave, defer-rescale (T13) ----
        float cmax = lg;
#pragma unroll
        for (int off = 32; off > 0; off >>= 1) cmax = fmaxf(cmax, __shfl_xor(cmax, off));
        if (cmax > m + 6.f) {          // wave-uniform branch
            const float sc = __expf(m - cmax);
            m = cmax; lsum *= sc;
            ap0 *= sc; ap1 *= sc; ap2 *= sc; ap3 *= sc;
#pragma unroll
            for (int d = 0; d < 16; ++d) ascd[d] *= sc;
#pragma unroll
            for (int d = 0; d < 24; ++d) aptd[d] *= sc;
        }
        const float p = __expf(lg - m);
        float psum = p;
#pragma unroll
        for (int off = 32; off > 0; off >>= 1) psum += __shfl_xor(psum, off);
        lsum += psum;
        plds[h][l] = p;
        // ---- v accumulation (f4-packed coalesced loads, independent chains) ----
        {
            float4 v0 = vsb[j], v1 = vsb[512 + j], v2 = vsb[1024 + j], v3 = vsb[1536 + j];
            ascd[0]  = fmaf(p, v0.x, ascd[0]);  ascd[1]  = fmaf(p, v0.y, ascd[1]);
            ascd[2]  = fmaf(p, v0.z, ascd[2]);  ascd[3]  = fmaf(p, v0.w, ascd[3]);
            ascd[4]  = fmaf(p, v1.x, ascd[4]);  ascd[5]  = fmaf(p, v1.y, ascd[5]);
            ascd[6]  = fmaf(p, v1.z, ascd[6]);  ascd[7]  = fmaf(p, v1.w, ascd[7]);
            ascd[8]  = fmaf(p, v2.x, ascd[8]);  ascd[9]  = fmaf(p, v2.y, ascd[9]);
            ascd[10] = fmaf(p, v2.z, ascd[10]); ascd[11] = fmaf(p, v2.w, ascd[11]);
            ascd[12] = fmaf(p, v3.x, ascd[12]); ascd[13] = fmaf(p, v3.y, ascd[13]);
            ascd[14] = fmaf(p, v3.z, ascd[14]); ascd[15] = fmaf(p, v3.w, ascd[15]);
#pragma unroll
            for (int g = 0; g < 6; ++g) {
                float4 w = vpb[g * 512 + j];
                aptd[4 * g + 0] = fmaf(p, w.x, aptd[4 * g + 0]);
                aptd[4 * g + 1] = fmaf(p, w.y, aptd[4 * g + 1]);
                aptd[4 * g + 2] = fmaf(p, w.z, aptd[4 * g + 2]);
                aptd[4 * g + 3] = fmaf(p, w.w, aptd[4 * g + 3]);
            }
        }
        // ---- pair accumulation: lane owns dim d=l; column reads 2-way (free); 4 chains ----
#pragma unroll
        for (int u = 0; u < 16; ++u) {
            float4 p4 = *(const float4*)&plds[h][4 * u];
            ap0 = fmaf(p4.x, pwc[4 * u + 0][l], ap0);
            ap1 = fmaf(p4.y, pwc[4 * u + 1][l], ap1);
            ap2 = fmaf(p4.z, pwc[4 * u + 2][l], ap2);
            ap3 = fmaf(p4.w, pwc[4 * u + 3][l], ap3);
        }
        // ---- write next chunk to other buffer (scalar stores) ----
        if (more) {
            int jj = t >> 4, u4 = (t & 15) * 4;
            pwt[nxt][jj][u4] = nA.x; pwt[nxt][jj][u4 + 1] = nA.y; pwt[nxt][jj][u4 + 2] = nA.z; pwt[nxt][jj][u4 + 3] = nA.w;
            int f2 = t + 512, jB = f2 >> 4, uB = (f2 & 15) * 4;
            pwt[nxt][jB][uB] = nB.x; pwt[nxt][jB][uB + 1] = nB.y; pwt[nxt][jB][uB + 2] = nB.z; pwt[nxt][jB][uB + 3] = nB.w;
        }
        __syncthreads();
    }

    // ---- epilogue: butterfly-reduce j-partials across 64 lanes ----
#pragma unroll
    for (int off = 32; off > 0; off >>= 1) {
#pragma unroll
        for (int d = 0; d < 16; ++d) ascd[d] += __shfl_xor(ascd[d], off);
#pragma unroll
        for (int d = 0; d < 24; ++d) aptd[d] += __shfl_xor(aptd[d], off);
    }
    const float ap = (ap0 + ap1) + (ap2 + ap3);
    const float inv_l = 1.f / lsum;
    float* fb = feats + (size_t)bi * 896;
    if (l < 16) fb[h * 16 + l] = ascd[l] * inv_l;             // m_scalar
    fb[384 + h * 64 + l] = ap * inv_l;                        // m_pair (lane owns d=l)
    const float tr0 = trans[bi * 3 + 0], tr1 = trans[bi * 3 + 1], tr2 = trans[bi * 3 + 2];
    if (l < 24) {
        const int pp = l / 3, r = l - pp * 3;
        const float c0 = aptd[pp * 3 + 0] * inv_l - tr0;
        const float c1 = aptd[pp * 3 + 1] * inv_l - tr1;
        const float c2 = aptd[pp * 3 + 2] * inv_l - tr2;
        const float* Rm = rot + (size_t)bi * 9 + r * 3;       // R[r][c]
        fb[128 + h * 24 + pp * 3 + r] = fmaf(c0, Rm[0], fmaf(c1, Rm[1], c2 * Rm[2]));
    }
    if (l < 8) {
        const float c0 = aptd[l * 3 + 0] * inv_l - tr0;
        const float c1 = aptd[l * 3 + 1] * inv_l - tr1;
        const float c2 = aptd[l * 3 + 2] * inv_l - tr2;
        fb[320 + h * 8 + l] = sqrtf(fmaf(c0, c0, fmaf(c1, c1, fmaf(c2, c2, EPSV))));
    }
}

// ---------------- output projection: 4 tokens x 192-col half per block ----------------
__global__ __launch_bounds__(256) void k_out(
    const float* __restrict__ feats, const float* __restrict__ Wout,
    const float* __restrict__ bout, float* __restrict__ out)
{
    __shared__ float fl[4][896];
    const int t = threadIdx.x;
    const int tile = blockIdx.x >> 1;
    const int half = blockIdx.x & 1;
    const int tok0 = tile * 4;
    {
        const float4* src = (const float4*)(feats + (size_t)tok0 * 896);
        float4* dst = (float4*)&fl[0][0];
        dst[t] = src[t];
        dst[t + 256] = src[t + 256];
        dst[t + 512] = src[t + 512];
        if (t < 128) dst[t + 768] = src[t + 768];   // 896 float4 total
    }
    __syncthreads();
    const int tok = t >> 6, l = t & 63;
    const int c0 = 192 * half;
    float acc0 = 0.f, acc1 = 0.f, acc2 = 0.f;
#pragma unroll 8
    for (int dd = 0; dd < 896; ++dd) {
        float fv = fl[tok][dd];
        const float* wr = Wout + (size_t)dd * 384 + c0;
        acc0 = fmaf(fv, wr[l], acc0);
        acc1 = fmaf(fv, wr[l + 64], acc1);
        acc2 = fmaf(fv, wr[l + 128], acc2);
    }
    float* ob = out + (size_t)(tok0 + tok) * 384 + c0;
    ob[l]       = acc0 + bout[c0 + l];
    ob[l + 64]  = acc1 + bout[c0 + l + 64];
    ob[l + 128] = acc2 + bout[c0 + l + 128];
}

extern "C" void kernel_launch(void* const* d_in, const int* in_sizes, int n_in,
                              void* d_out, int out_size, void* d_ws, size_t ws_size,
                              hipStream_t stream) {
    const float* x        = (const float*)d_in[0];
    const float* pairw    = (const float*)d_in[1];
    const float* rot      = (const float*)d_in[2];
    const float* trans    = (const float*)d_in[3];
    const int*   pos      = (const int*)d_in[4];
    const float* Wq_s     = (const float*)d_in[6];
    const float* Wk_s     = (const float*)d_in[7];
    const float* Wv_s     = (const float*)d_in[8];
    const float* Wq_p     = (const float*)d_in[9];
    const float* Wk_p     = (const float*)d_in[10];
    const float* Wv_p     = (const float*)d_in[11];
    const float* pweights = (const float*)d_in[12];
    const float* Wpair    = (const float*)d_in[13];
    const float* bpair    = (const float*)d_in[14];
    const float* Wout     = (const float*)d_in[15];
    const float* bout     = (const float*)d_in[16];
    float* out = (float*)d_out;

    float* ws = (float*)d_ws;
    float* cos_t = ws;   ws += 4096;
    float* sin_t = ws;   ws += 4096;
    float* qsg = ws;     ws += BB * HH * NN * 16;
    float* qpg = ws;     ws += BB * HH * NN * 12;
    float* qqg = ws;     ws += BB * HH * NN;
    float4* kst = (float4*)ws; ws += BB * HH * NN * 16;   // [bh][4][N] f4
    float* kpt = ws;     ws += BB * HH * NN * 12;         // [bh][3][N] f4
    float* kkg = ws;     ws += BB * HH * NN;
    float4* vst = (float4*)ws; ws += BB * HH * NN * 16;   // [bh][4][N] f4
    float* vpt = ws;     ws += BB * HH * NN * 24;         // [bh][6][N] f4
    float* feats = ws;   ws += BB * NN * 896;

    k_rope<<<2, 256, 0, stream>>>(cos_t, sin_t);
    k_proj<<<(BB * NN) / 8 * 2, 256, 0, stream>>>(x, rot, trans, pos,
        Wq_s, Wk_s, Wv_s, Wq_p, Wk_p, Wv_p, cos_t, sin_t,
        qsg, qpg, qqg, kst, kpt, kkg, vst, vpt);
    k_attn<<<BB * NN, 512, 0, stream>>>(pairw, rot, trans, Wpair, bpair, pweights,
        qsg, qpg, qqg, kst, (const float4*)kpt, kkg, vst, (const float4*)vpt, feats);
    k_out<<<(BB * NN) / 4 * 2, 256, 0, stream>>>(feats, Wout, bout, out);

    (void)in_sizes; (void)n_in; (void)out_size; (void)ws_size;
}

// Round 9
// 461.797 us; speedup vs baseline: 1.2284x; 1.2284x over previous
//
#include <hip/hip_runtime.h>
#include <math.h>

#define BB 4
#define NN 512
#define DIMX 384
#define HH 8
#define PDD 64
#define JC 64
#define PWPAD 65   // odd pad: scalar row/col reads both 2-way banks (free, m136)

static constexpr float EPSV = 1e-8f;
static constexpr float SCALAR_SCALE = 0.14433756729740643f;  // (3*16)^-0.5
static constexpr float POINT_SCALE  = 0.1360827634879543f;   // (3*4*4.5)^-0.5
static constexpr float PAIR_SCALE   = 0.5773502691896258f;   // 3^-0.5

static __device__ __forceinline__ unsigned pack_bf16(float a, float b) {
    return (__float_as_uint(a) >> 16) | (__float_as_uint(b) & 0xffff0000u);
}

// ---------------- rope table ----------------
__global__ void k_rope(float* __restrict__ cos_t, float* __restrict__ sin_t) {
    int n = blockIdx.x * blockDim.x + threadIdx.x;
    if (n >= NN) return;
#pragma unroll
    for (int i = 0; i < 8; ++i) {
        float invf = powf(10000.0f, -(float)i / 8.0f);
        float f = (float)n * invf;
        cos_t[n * 8 + i] = cosf(f);
        sin_t[n * 8 + i] = sinf(f);
    }
}

// ---------------- pair-bias precompute: bias[b*N+i][h][j] ----------------
// One block per (b,i); 4 chunks of 128 j staged as bf16; each thread owns
// (j, 4 heads) so each pw value feeds 4 fma from 1 read (+ W broadcast f4).
__global__ __launch_bounds__(256) void k_bias(
    const float* __restrict__ pairw, const float* __restrict__ Wpair,
    const float* __restrict__ bpair, float* __restrict__ biasg)
{
    __shared__ unsigned short pwb[128][70];   // bf16 tile, pad 70 (3j+d banks, 2-way)
    __shared__ float Wl[64][8];               // [d][h] as given
    const int t = threadIdx.x;
    const int bi = blockIdx.x;

    if (t < 64) {
        *(float4*)&Wl[t][0] = *(const float4*)&Wpair[t * 8];
        *(float4*)&Wl[t][4] = *(const float4*)&Wpair[t * 8 + 4];
    }
    const int jl = t & 127, hg = t >> 7;      // heads 4hg..4hg+3
    const float bp0 = bpair[4 * hg + 0], bp1 = bpair[4 * hg + 1];
    const float bp2 = bpair[4 * hg + 2], bp3 = bpair[4 * hg + 3];
    const float* src = pairw + (size_t)bi * NN * PDD;
    float* dst = biasg + (size_t)bi * HH * NN;

    for (int c = 0; c < 4; ++c) {
        __syncthreads();
        {   // stage 128x64 floats -> bf16
            const float4* s4 = (const float4*)(src + (size_t)c * 128 * PDD);
#pragma unroll
            for (int k = 0; k < 8; ++k) {
                int f = t + 256 * k;
                int j = f >> 4, d4 = (f & 15) * 4;
                float4 v = s4[f];
                *(unsigned*)&pwb[j][d4]     = pack_bf16(v.x, v.y);
                *(unsigned*)&pwb[j][d4 + 2] = pack_bf16(v.z, v.w);
            }
        }
        __syncthreads();
        float a0 = 0.f, a1 = 0.f, a2 = 0.f, a3 = 0.f;
#pragma unroll
        for (int d2 = 0; d2 < 32; ++d2) {
            unsigned pr = *(const unsigned*)&pwb[jl][2 * d2];
            float p0 = __uint_as_float(pr << 16);
            float p1 = __uint_as_float(pr & 0xffff0000u);
            float4 w0 = *(const float4*)&Wl[2 * d2][4 * hg];
            float4 w1 = *(const float4*)&Wl[2 * d2 + 1][4 * hg];
            a0 = fmaf(p0, w0.x, fmaf(p1, w1.x, a0));
            a1 = fmaf(p0, w0.y, fmaf(p1, w1.y, a1));
            a2 = fmaf(p0, w0.z, fmaf(p1, w1.z, a2));
            a3 = fmaf(p0, w0.w, fmaf(p1, w1.w, a3));
        }
        const int j = c * 128 + jl;
        dst[(size_t)(4 * hg + 0) * NN + j] = (a0 + bp0) * PAIR_SCALE;
        dst[(size_t)(4 * hg + 1) * NN + j] = (a1 + bp1) * PAIR_SCALE;
        dst[(size_t)(4 * hg + 2) * NN + j] = (a2 + bp2) * PAIR_SCALE;
        dst[(size_t)(4 * hg + 3) * NN + j] = (a3 + bp3) * PAIR_SCALE;
    }
}

// ---------------- projections + transforms (column-half split) ----------------
__global__ __launch_bounds__(256) void k_proj(
    const float* __restrict__ x, const float* __restrict__ rot,
    const float* __restrict__ trans, const int* __restrict__ pos_ids,
    const float* __restrict__ Wq_s, const float* __restrict__ Wk_s, const float* __restrict__ Wv_s,
    const float* __restrict__ Wq_p, const float* __restrict__ Wk_p, const float* __restrict__ Wv_p,
    const float* __restrict__ cos_t, const float* __restrict__ sin_t,
    float* __restrict__ qsg, float* __restrict__ qpg, float* __restrict__ qqg,
    float4* __restrict__ kst, float* __restrict__ kpt, float* __restrict__ kkg,
    float4* __restrict__ vst, float* __restrict__ vpt)
{
    __shared__ float xl[8][DIMX];
    __shared__ float raw[8][384];
    const int t = threadIdx.x;
    const int tile = blockIdx.x >> 1;
    const int half = blockIdx.x & 1;
    const int tok0 = tile * 8;

    {
        const float4* xg = (const float4*)(x + (size_t)tok0 * DIMX);
        float4* xl4 = (float4*)&xl[0][0];
#pragma unroll
        for (int k = 0; k < 3; ++k) xl4[t + 256 * k] = xg[t + 256 * k];
    }
    __syncthreads();

    const int tok = t >> 5, l = t & 31;
    {
        float4 acc[3];
        const float* wb[3];
        int st[3];
#pragma unroll
        for (int m = 0; m < 3; ++m) {
            int f = l + 32 * m + 96 * half;
            const float* w; int out, c;
            if (f < 32)       { w = Wq_s; out = 128; c = 4 * f; }
            else if (f < 64)  { w = Wk_s; out = 128; c = 4 * f - 128; }
            else if (f < 96)  { w = Wv_s; out = 128; c = 4 * f - 256; }
            else if (f < 120) { w = Wq_p; out = 96;  c = 4 * f - 384; }
            else if (f < 144) { w = Wk_p; out = 96;  c = 4 * f - 480; }
            else              { w = Wv_p; out = 192; c = 4 * f - 576; }
            wb[m] = w + c; st[m] = out;
            acc[m] = make_float4(0.f, 0.f, 0.f, 0.f);
        }
        for (int dd = 0; dd < DIMX; ++dd) {
            float xv = xl[tok][dd];
#pragma unroll
            for (int m = 0; m < 3; ++m) {
                float4 wv = *(const float4*)(wb[m] + (size_t)dd * st[m]);
                acc[m].x = fmaf(xv, wv.x, acc[m].x);
                acc[m].y = fmaf(xv, wv.y, acc[m].y);
                acc[m].z = fmaf(xv, wv.z, acc[m].z);
                acc[m].w = fmaf(xv, wv.w, acc[m].w);
            }
        }
#pragma unroll
        for (int m = 0; m < 3; ++m)
            *(float4*)&raw[tok][4 * (l + 32 * m)] = acc[m];
    }
    __syncthreads();

    const int h = l >> 2, q = l & 3;
    const int n_g = tok0 + tok;
    const int b = n_g / NN;
    const int nloc = n_g - b * NN;
    const int bh = b * HH + h;
    const size_t rowi = (size_t)bh * NN + nloc;

    if (half == 0) {
        const int pos = pos_ids[n_g];
        float qv[4], kv[4], vv[4];
#pragma unroll
        for (int dd0 = 0; dd0 < 4; ++dd0) {
            int dd = q * 4 + dd0;
            int i8 = dd & 7;
            float c = cos_t[pos * 8 + i8], s = sin_t[pos * 8 + i8];
            float xq = raw[tok][h * 16 + dd];
            float rq = (dd < 8) ? -raw[tok][h * 16 + dd + 8] : raw[tok][h * 16 + dd - 8];
            qv[dd0] = fmaf(xq, c, rq * s);
            float xk = raw[tok][128 + h * 16 + dd];
            float rk = (dd < 8) ? -raw[tok][128 + h * 16 + dd + 8] : raw[tok][128 + h * 16 + dd - 8];
            kv[dd0] = fmaf(xk, c, rk * s);
            vv[dd0] = raw[tok][256 + h * 16 + dd];
        }
        *(float4*)&qsg[rowi * 16 + q * 4] = make_float4(qv[0], qv[1], qv[2], qv[3]);
        kst[(size_t)bh * 2048 + q * 512 + nloc] = make_float4(kv[0], kv[1], kv[2], kv[3]);
        vst[(size_t)bh * 2048 + q * 512 + nloc] = make_float4(vv[0], vv[1], vv[2], vv[3]);
    } else {
        const float* Rm = rot + (size_t)n_g * 9;
        const float trv[3] = {trans[n_g * 3 + 0], trans[n_g * 3 + 1], trans[n_g * 3 + 2]};
        float qqp = 0.f, kkp = 0.f;
        {
            float pc[3], kc[3];
#pragma unroll
            for (int c = 0; c < 3; ++c) {
                pc[c] = raw[tok][h * 12 + q * 3 + c];
                kc[c] = raw[tok][96 + h * 12 + q * 3 + c];
            }
#pragma unroll
            for (int r = 0; r < 3; ++r) {
                float vq = trv[r], vk = trv[r];
#pragma unroll
                for (int c = 0; c < 3; ++c) {
                    vq = fmaf(pc[c], Rm[c * 3 + r], vq);
                    vk = fmaf(kc[c], Rm[c * 3 + r], vk);
                }
                qpg[rowi * 12 + q * 3 + r] = vq;
                int d = q * 3 + r;   // 0..11
                kpt[(size_t)bh * 6144 + (d >> 2) * 2048 + nloc * 4 + (d & 3)] = vk;
                qqp = fmaf(vq, vq, qqp);
                kkp = fmaf(vk, vk, kkp);
            }
        }
        qqp += __shfl_xor(qqp, 1); qqp += __shfl_xor(qqp, 2);
        kkp += __shfl_xor(kkp, 1); kkp += __shfl_xor(kkp, 2);
        if (q == 0) { qqg[rowi] = qqp; kkg[rowi] = kkp; }
#pragma unroll
        for (int pp = 0; pp < 2; ++pp) {
            int p = q + 4 * pp;
            float pc[3];
#pragma unroll
            for (int c = 0; c < 3; ++c) pc[c] = raw[tok][192 + h * 24 + p * 3 + c];
#pragma unroll
            for (int r = 0; r < 3; ++r) {
                float v = trv[r];
#pragma unroll
                for (int c = 0; c < 3; ++c) v = fmaf(pc[c], Rm[c * 3 + r], v);
                int d = p * 3 + r;   // 0..23
                vpt[(size_t)bh * 12288 + (d >> 2) * 2048 + nloc * 4 + (d & 3)] = v;
            }
        }
    }
}

// ---------------- fused attention: 512 threads, wave = head, lane = j ----------------
// Bias phase removed (precomputed by k_bias). Single pw buffer -> ~20KB LDS.
__global__ __launch_bounds__(512, 2) void k_attn(
    const float* __restrict__ pairw, const float* __restrict__ biasg,
    const float* __restrict__ rot, const float* __restrict__ trans,
    const float* __restrict__ pweights,
    const float* __restrict__ qsg, const float* __restrict__ qpg, const float* __restrict__ qqg,
    const float4* __restrict__ kst, const float4* __restrict__ kpt, const float* __restrict__ kkg,
    const float4* __restrict__ vst, const float4* __restrict__ vpt,
    float* __restrict__ feats)
{
    __shared__ float pwt[JC][PWPAD];   // single-buffer padded tile (~16.6KB)
    __shared__ float plds[HH][JC];     // per-head probs (same-wave write->read)
    __shared__ float qsh[HH][16];
    __shared__ float qph[HH][12];
    __shared__ float qqh[HH];

    const int t = threadIdx.x;
    const int bi = blockIdx.x;
    const int b = bi >> 9;
    const int h = t >> 6, l = t & 63;  // wave = head, lane = j-in-chunk

    const int bh = b * HH + h;
    const size_t rowq = (size_t)bh * NN + (bi & 511);
    if (l < 16) qsh[h][l] = qsg[rowq * 16 + l];
    if (l < 12) qph[h][l] = qpg[rowq * 12 + l];
    if (l == 0) qqh[h] = qqg[rowq];

    const float coefP = -0.5f * log1pf(__expf(pweights[h])) * POINT_SCALE;

    const float4* ksb = kst + (size_t)bh * 2048;   // [4][512] f4
    const float4* vsb = vst + (size_t)bh * 2048;   // [4][512] f4
    const float4* kpb = kpt + (size_t)bh * 1536;   // [3][512] f4
    const float4* vpb = vpt + (size_t)bh * 3072;   // [6][512] f4
    const float*  kkb = kkg + (size_t)bh * 512;
    const float*  biasrow = biasg + ((size_t)bi * HH + h) * NN;

    const float4* pwsrc = (const float4*)(pairw + (size_t)bi * NN * PDD);

    float m = -3.0e38f, lsum = 0.f;
    float ap0 = 0.f, ap1 = 0.f, ap2 = 0.f, ap3 = 0.f;
    float ascd[16], aptd[24];
#pragma unroll
    for (int d = 0; d < 16; ++d) ascd[d] = 0.f;
#pragma unroll
    for (int d = 0; d < 24; ++d) aptd[d] = 0.f;

    for (int c = 0; c < NN / JC; ++c) {
        __syncthreads();   // everyone done reading pwt from prev chunk
        {   // stage pairwise chunk (scalar stores, pad-65)
            const float4* s = pwsrc + (size_t)c * 1024;
            float4 vA = s[t], vB = s[t + 512];
            int jA = t >> 4, dA = (t & 15) * 4;
            pwt[jA][dA] = vA.x; pwt[jA][dA + 1] = vA.y; pwt[jA][dA + 2] = vA.z; pwt[jA][dA + 3] = vA.w;
            int f2 = t + 512, jB = f2 >> 4, dB = (f2 & 15) * 4;
            pwt[jB][dB] = vB.x; pwt[jB][dB + 1] = vB.y; pwt[jB][dB + 2] = vB.z; pwt[jB][dB + 3] = vB.w;
        }
        __syncthreads();
        const int j = c * JC + l;
        const float bias = biasrow[j];   // precomputed, coalesced
        // ---- logit (f4-packed d-major loads, all stride-1 coalesced) ----
        float lg;
        {
            const float4 qs0 = *(const float4*)&qsh[h][0];
            const float4 qs1 = *(const float4*)&qsh[h][4];
            const float4 qs2 = *(const float4*)&qsh[h][8];
            const float4 qs3 = *(const float4*)&qsh[h][12];
            float4 k0 = ksb[j], k1 = ksb[512 + j], k2 = ksb[1024 + j], k3 = ksb[1536 + j];
            float d0 = 0.f, d1 = 0.f;
            d0 = fmaf(qs0.x, k0.x, d0); d0 = fmaf(qs0.y, k0.y, d0);
            d0 = fmaf(qs0.z, k0.z, d0); d0 = fmaf(qs0.w, k0.w, d0);
            d1 = fmaf(qs1.x, k1.x, d1); d1 = fmaf(qs1.y, k1.y, d1);
            d1 = fmaf(qs1.z, k1.z, d1); d1 = fmaf(qs1.w, k1.w, d1);
            d0 = fmaf(qs2.x, k2.x, d0); d0 = fmaf(qs2.y, k2.y, d0);
            d0 = fmaf(qs2.z, k2.z, d0); d0 = fmaf(qs2.w, k2.w, d0);
            d1 = fmaf(qs3.x, k3.x, d1); d1 = fmaf(qs3.y, k3.y, d1);
            d1 = fmaf(qs3.z, k3.z, d1); d1 = fmaf(qs3.w, k3.w, d1);
            const float4 qp0 = *(const float4*)&qph[h][0];
            const float4 qp1 = *(const float4*)&qph[h][4];
            const float4 qp2 = *(const float4*)&qph[h][8];
            float4 P0 = kpb[j], P1 = kpb[512 + j], P2 = kpb[1024 + j];
            float e0 = 0.f, e1 = 0.f;
            e0 = fmaf(qp0.x, P0.x, e0); e0 = fmaf(qp0.y, P0.y, e0);
            e0 = fmaf(qp0.z, P0.z, e0); e0 = fmaf(qp0.w, P0.w, e0);
            e1 = fmaf(qp1.x, P1.x, e1); e1 = fmaf(qp1.y, P1.y, e1);
            e1 = fmaf(qp1.z, P1.z, e1); e1 = fmaf(qp1.w, P1.w, e1);
            e0 = fmaf(qp2.x, P2.x, e0); e0 = fmaf(qp2.y, P2.y, e0);
            e0 = fmaf(qp2.z, P2.z, e0); e0 = fmaf(qp2.w, P2.w, e0);
            float dist = qqh[h] + kkb[j] - 2.f * (e0 + e1);
            lg = fmaf(d0 + d1, SCALAR_SCALE, fmaf(coefP, dist, bias));
        }
        // ---- online softmax across the 64-lane wave, defer-rescale (T13) ----
        float cmax = lg;
#pragma unroll
        for (int off = 32; off > 0; off >>= 1) cmax = fmaxf(cmax, __shfl_xor(cmax, off));
        if (cmax > m + 6.f) {          // wave-uniform branch
            const float sc = __expf(m - cmax);
            m = cmax; lsum *= sc;
            ap0 *= sc; ap1 *= sc; ap2 *= sc; ap3 *= sc;
#pragma unroll
            for (int d = 0; d < 16; ++d) ascd[d] *= sc;
#pragma unroll
            for (int d = 0; d < 24; ++d) aptd[d] *= sc;
        }
        const float p = __expf(lg - m);
        float psum = p;
#pragma unroll
        for (int off = 32; off > 0; off >>= 1) psum += __shfl_xor(psum, off);
        lsum += psum;
        plds[h][l] = p;
        // ---- v accumulation (f4-packed coalesced loads) ----
        {
            float4 v0 = vsb[j], v1 = vsb[512 + j], v2 = vsb[1024 + j], v3 = vsb[1536 + j];
            ascd[0]  = fmaf(p, v0.x, ascd[0]);  ascd[1]  = fmaf(p, v0.y, ascd[1]);
            ascd[2]  = fmaf(p, v0.z, ascd[2]);  ascd[3]  = fmaf(p, v0.w, ascd[3]);
            ascd[4]  = fmaf(p, v1.x, ascd[4]);  ascd[5]  = fmaf(p, v1.y, ascd[5]);
            ascd[6]  = fmaf(p, v1.z, ascd[6]);  ascd[7]  = fmaf(p, v1.w, ascd[7]);
            ascd[8]  = fmaf(p, v2.x, ascd[8]);  ascd[9]  = fmaf(p, v2.y, ascd[9]);
            ascd[10] = fmaf(p, v2.z, ascd[10]); ascd[11] = fmaf(p, v2.w, ascd[11]);
            ascd[12] = fmaf(p, v3.x, ascd[12]); ascd[13] = fmaf(p, v3.y, ascd[13]);
            ascd[14] = fmaf(p, v3.z, ascd[14]); ascd[15] = fmaf(p, v3.w, ascd[15]);
#pragma unroll
            for (int g = 0; g < 6; ++g) {
                float4 w = vpb[g * 512 + j];
                aptd[4 * g + 0] = fmaf(p, w.x, aptd[4 * g + 0]);
                aptd[4 * g + 1] = fmaf(p, w.y, aptd[4 * g + 1]);
                aptd[4 * g + 2] = fmaf(p, w.z, aptd[4 * g + 2]);
                aptd[4 * g + 3] = fmaf(p, w.w, aptd[4 * g + 3]);
            }
        }
        // ---- pair accumulation: lane owns dim d=l; col reads 2-way (free); 4 chains ----
#pragma unroll
        for (int u = 0; u < 16; ++u) {
            float4 p4 = *(const float4*)&plds[h][4 * u];
            ap0 = fmaf(p4.x, pwt[4 * u + 0][l], ap0);
            ap1 = fmaf(p4.y, pwt[4 * u + 1][l], ap1);
            ap2 = fmaf(p4.z, pwt[4 * u + 2][l], ap2);
            ap3 = fmaf(p4.w, pwt[4 * u + 3][l], ap3);
        }
    }

    // ---- epilogue: butterfly-reduce j-partials across 64 lanes ----
#pragma unroll
    for (int off = 32; off > 0; off >>= 1) {
#pragma unroll
        for (int d = 0; d < 16; ++d) ascd[d] += __shfl_xor(ascd[d], off);
#pragma unroll
        for (int d = 0; d < 24; ++d) aptd[d] += __shfl_xor(aptd[d], off);
    }
    const float ap = (ap0 + ap1) + (ap2 + ap3);
    const float inv_l = 1.f / lsum;
    float* fb = feats + (size_t)bi * 896;
    if (l < 16) fb[h * 16 + l] = ascd[l] * inv_l;             // m_scalar
    fb[384 + h * 64 + l] = ap * inv_l;                        // m_pair (lane owns d=l)
    const float tr0 = trans[bi * 3 + 0], tr1 = trans[bi * 3 + 1], tr2 = trans[bi * 3 + 2];
    if (l < 24) {
        const int pp = l / 3, r = l - pp * 3;
        const float c0 = aptd[pp * 3 + 0] * inv_l - tr0;
        const float c1 = aptd[pp * 3 + 1] * inv_l - tr1;
        const float c2 = aptd[pp * 3 + 2] * inv_l - tr2;
        const float* Rm = rot + (size_t)bi * 9 + r * 3;       // R[r][c]
        fb[128 + h * 24 + pp * 3 + r] = fmaf(c0, Rm[0], fmaf(c1, Rm[1], c2 * Rm[2]));
    }
    if (l < 8) {
        const float c0 = aptd[l * 3 + 0] * inv_l - tr0;
        const float c1 = aptd[l * 3 + 1] * inv_l - tr1;
        const float c2 = aptd[l * 3 + 2] * inv_l - tr2;
        fb[320 + h * 8 + l] = sqrtf(fmaf(c0, c0, fmaf(c1, c1, fmaf(c2, c2, EPSV))));
    }
}

// ---------------- output projection: 4 tokens x 192-col half per block ----------------
__global__ __launch_bounds__(256) void k_out(
    const float* __restrict__ feats, const float* __restrict__ Wout,
    const float* __restrict__ bout, float* __restrict__ out)
{
    __shared__ float fl[4][896];
    const int t = threadIdx.x;
    const int tile = blockIdx.x >> 1;
    const int half = blockIdx.x & 1;
    const int tok0 = tile * 4;
    {
        const float4* src = (const float4*)(feats + (size_t)tok0 * 896);
        float4* dst = (float4*)&fl[0][0];
        dst[t] = src[t];
        dst[t + 256] = src[t + 256];
        dst[t + 512] = src[t + 512];
        if (t < 128) dst[t + 768] = src[t + 768];   // 896 float4 total
    }
    __syncthreads();
    const int tok = t >> 6, l = t & 63;
    const int c0 = 192 * half;
    float acc0 = 0.f, acc1 = 0.f, acc2 = 0.f;
#pragma unroll 8
    for (int dd = 0; dd < 896; ++dd) {
        float fv = fl[tok][dd];
        const float* wr = Wout + (size_t)dd * 384 + c0;
        acc0 = fmaf(fv, wr[l], acc0);
        acc1 = fmaf(fv, wr[l + 64], acc1);
        acc2 = fmaf(fv, wr[l + 128], acc2);
    }
    float* ob = out + (size_t)(tok0 + tok) * 384 + c0;
    ob[l]       = acc0 + bout[c0 + l];
    ob[l + 64]  = acc1 + bout[c0 + l + 64];
    ob[l + 128] = acc2 + bout[c0 + l + 128];
}

extern "C" void kernel_launch(void* const* d_in, const int* in_sizes, int n_in,
                              void* d_out, int out_size, void* d_ws, size_t ws_size,
                              hipStream_t stream) {
    const float* x        = (const float*)d_in[0];
    const float* pairw    = (const float*)d_in[1];
    const float* rot      = (const float*)d_in[2];
    const float* trans    = (const float*)d_in[3];
    const int*   pos      = (const int*)d_in[4];
    const float* Wq_s     = (const float*)d_in[6];
    const float* Wk_s     = (const float*)d_in[7];
    const float* Wv_s     = (const float*)d_in[8];
    const float* Wq_p     = (const float*)d_in[9];
    const float* Wk_p     = (const float*)d_in[10];
    const float* Wv_p     = (const float*)d_in[11];
    const float* pweights = (const float*)d_in[12];
    const float* Wpair    = (const float*)d_in[13];
    const float* bpair    = (const float*)d_in[14];
    const float* Wout     = (const float*)d_in[15];
    const float* bout     = (const float*)d_in[16];
    float* out = (float*)d_out;

    float* ws = (float*)d_ws;
    float* cos_t = ws;   ws += 4096;
    float* sin_t = ws;   ws += 4096;
    float* qsg = ws;     ws += BB * HH * NN * 16;
    float* qpg = ws;     ws += BB * HH * NN * 12;
    float* qqg = ws;     ws += BB * HH * NN;
    float4* kst = (float4*)ws; ws += BB * HH * NN * 16;   // [bh][4][N] f4
    float* kpt = ws;     ws += BB * HH * NN * 12;         // [bh][3][N] f4
    float* kkg = ws;     ws += BB * HH * NN;
    float4* vst = (float4*)ws; ws += BB * HH * NN * 16;   // [bh][4][N] f4
    float* vpt = ws;     ws += BB * HH * NN * 24;         // [bh][6][N] f4
    float* feats = ws;   ws += BB * NN * 896;
    float* biasg = ws;   ws += (size_t)BB * NN * HH * NN; // 33.5 MB

    k_rope<<<2, 256, 0, stream>>>(cos_t, sin_t);
    k_bias<<<BB * NN, 256, 0, stream>>>(pairw, Wpair, bpair, biasg);
    k_proj<<<(BB * NN) / 8 * 2, 256, 0, stream>>>(x, rot, trans, pos,
        Wq_s, Wk_s, Wv_s, Wq_p, Wk_p, Wv_p, cos_t, sin_t,
        qsg, qpg, qqg, kst, kpt, kkg, vst, vpt);
    k_attn<<<BB * NN, 512, 0, stream>>>(pairw, biasg, rot, trans, pweights,
        qsg, qpg, qqg, kst, (const float4*)kpt, kkg, vst, (const float4*)vpt, feats);
    k_out<<<(BB * NN) / 4 * 2, 256, 0, stream>>>(feats, Wout, bout, out);

    (void)in_sizes; (void)n_in; (void)out_size; (void)ws_size;
}

// Round 10
// 443.764 us; speedup vs baseline: 1.2783x; 1.0406x over previous
//
#include <hip/hip_runtime.h>
#include <math.h>

#define BB 4
#define NN 512
#define DIMX 384
#define HH 8
#define PDD 64
#define JC 64
#define PWPAD 66   // f2-aligned rows (264B); col reads (2j+l)%32 and f2 row-slices both min-cost

static constexpr float EPSV = 1e-8f;
static constexpr float SCALAR_SCALE = 0.14433756729740643f;  // (3*16)^-0.5
static constexpr float POINT_SCALE  = 0.1360827634879543f;   // (3*4*4.5)^-0.5
static constexpr float PAIR_SCALE   = 0.5773502691896258f;   // 3^-0.5

// ---------------- rope table ----------------
__global__ void k_rope(float* __restrict__ cos_t, float* __restrict__ sin_t) {
    int n = blockIdx.x * blockDim.x + threadIdx.x;
    if (n >= NN) return;
#pragma unroll
    for (int i = 0; i < 8; ++i) {
        float invf = powf(10000.0f, -(float)i / 8.0f);
        float f = (float)n * invf;
        cos_t[n * 8 + i] = cosf(f);
        sin_t[n * 8 + i] = sinf(f);
    }
}

// ---------------- projections + transforms (column-half split) ----------------
__global__ __launch_bounds__(256) void k_proj(
    const float* __restrict__ x, const float* __restrict__ rot,
    const float* __restrict__ trans, const int* __restrict__ pos_ids,
    const float* __restrict__ Wq_s, const float* __restrict__ Wk_s, const float* __restrict__ Wv_s,
    const float* __restrict__ Wq_p, const float* __restrict__ Wk_p, const float* __restrict__ Wv_p,
    const float* __restrict__ cos_t, const float* __restrict__ sin_t,
    float* __restrict__ qsg, float* __restrict__ qpg, float* __restrict__ qqg,
    float4* __restrict__ kst, float* __restrict__ kpt, float* __restrict__ kkg,
    float4* __restrict__ vst, float* __restrict__ vpt)
{
    __shared__ float xl[8][DIMX];
    __shared__ float raw[8][384];
    const int t = threadIdx.x;
    const int tile = blockIdx.x >> 1;
    const int half = blockIdx.x & 1;
    const int tok0 = tile * 8;

    {
        const float4* xg = (const float4*)(x + (size_t)tok0 * DIMX);
        float4* xl4 = (float4*)&xl[0][0];
#pragma unroll
        for (int k = 0; k < 3; ++k) xl4[t + 256 * k] = xg[t + 256 * k];
    }
    __syncthreads();

    const int tok = t >> 5, l = t & 31;
    {
        float4 acc[3];
        const float* wb[3];
        int st[3];
#pragma unroll
        for (int m = 0; m < 3; ++m) {
            int f = l + 32 * m + 96 * half;
            const float* w; int out, c;
            if (f < 32)       { w = Wq_s; out = 128; c = 4 * f; }
            else if (f < 64)  { w = Wk_s; out = 128; c = 4 * f - 128; }
            else if (f < 96)  { w = Wv_s; out = 128; c = 4 * f - 256; }
            else if (f < 120) { w = Wq_p; out = 96;  c = 4 * f - 384; }
            else if (f < 144) { w = Wk_p; out = 96;  c = 4 * f - 480; }
            else              { w = Wv_p; out = 192; c = 4 * f - 576; }
            wb[m] = w + c; st[m] = out;
            acc[m] = make_float4(0.f, 0.f, 0.f, 0.f);
        }
        for (int dd = 0; dd < DIMX; ++dd) {
            float xv = xl[tok][dd];
#pragma unroll
            for (int m = 0; m < 3; ++m) {
                float4 wv = *(const float4*)(wb[m] + (size_t)dd * st[m]);
                acc[m].x = fmaf(xv, wv.x, acc[m].x);
                acc[m].y = fmaf(xv, wv.y, acc[m].y);
                acc[m].z = fmaf(xv, wv.z, acc[m].z);
                acc[m].w = fmaf(xv, wv.w, acc[m].w);
            }
        }
#pragma unroll
        for (int m = 0; m < 3; ++m)
            *(float4*)&raw[tok][4 * (l + 32 * m)] = acc[m];
    }
    __syncthreads();

    const int h = l >> 2, q = l & 3;
    const int n_g = tok0 + tok;
    const int b = n_g / NN;
    const int nloc = n_g - b * NN;
    const int bh = b * HH + h;
    const size_t rowi = (size_t)bh * NN + nloc;

    if (half == 0) {
        const int pos = pos_ids[n_g];
        float qv[4], kv[4], vv[4];
#pragma unroll
        for (int dd0 = 0; dd0 < 4; ++dd0) {
            int dd = q * 4 + dd0;
            int i8 = dd & 7;
            float c = cos_t[pos * 8 + i8], s = sin_t[pos * 8 + i8];
            float xq = raw[tok][h * 16 + dd];
            float rq = (dd < 8) ? -raw[tok][h * 16 + dd + 8] : raw[tok][h * 16 + dd - 8];
            qv[dd0] = fmaf(xq, c, rq * s);
            float xk = raw[tok][128 + h * 16 + dd];
            float rk = (dd < 8) ? -raw[tok][128 + h * 16 + dd + 8] : raw[tok][128 + h * 16 + dd - 8];
            kv[dd0] = fmaf(xk, c, rk * s);
            vv[dd0] = raw[tok][256 + h * 16 + dd];
        }
        *(float4*)&qsg[rowi * 16 + q * 4] = make_float4(qv[0], qv[1], qv[2], qv[3]);
        kst[(size_t)bh * 2048 + q * 512 + nloc] = make_float4(kv[0], kv[1], kv[2], kv[3]);
        vst[(size_t)bh * 2048 + q * 512 + nloc] = make_float4(vv[0], vv[1], vv[2], vv[3]);
    } else {
        const float* Rm = rot + (size_t)n_g * 9;
        const float trv[3] = {trans[n_g * 3 + 0], trans[n_g * 3 + 1], trans[n_g * 3 + 2]};
        float qqp = 0.f, kkp = 0.f;
        {
            float pc[3], kc[3];
#pragma unroll
            for (int c = 0; c < 3; ++c) {
                pc[c] = raw[tok][h * 12 + q * 3 + c];
                kc[c] = raw[tok][96 + h * 12 + q * 3 + c];
            }
#pragma unroll
            for (int r = 0; r < 3; ++r) {
                float vq = trv[r], vk = trv[r];
#pragma unroll
                for (int c = 0; c < 3; ++c) {
                    vq = fmaf(pc[c], Rm[c * 3 + r], vq);
                    vk = fmaf(kc[c], Rm[c * 3 + r], vk);
                }
                qpg[rowi * 12 + q * 3 + r] = vq;
                int d = q * 3 + r;   // 0..11
                kpt[(size_t)bh * 6144 + (d >> 2) * 2048 + nloc * 4 + (d & 3)] = vk;
                qqp = fmaf(vq, vq, qqp);
                kkp = fmaf(vk, vk, kkp);
            }
        }
        qqp += __shfl_xor(qqp, 1); qqp += __shfl_xor(qqp, 2);
        kkp += __shfl_xor(kkp, 1); kkp += __shfl_xor(kkp, 2);
        if (q == 0) { qqg[rowi] = qqp; kkg[rowi] = kkp; }
#pragma unroll
        for (int pp = 0; pp < 2; ++pp) {
            int p = q + 4 * pp;
            float pc[3];
#pragma unroll
            for (int c = 0; c < 3; ++c) pc[c] = raw[tok][192 + h * 24 + p * 3 + c];
#pragma unroll
            for (int r = 0; r < 3; ++r) {
                float v = trv[r];
#pragma unroll
                for (int c = 0; c < 3; ++c) v = fmaf(pc[c], Rm[c * 3 + r], v);
                int d = p * 3 + r;   // 0..23
                vpt[(size_t)bh * 12288 + (d >> 2) * 2048 + nloc * 4 + (d & 3)] = v;
            }
        }
    }
}

// ---------------- fused attention: 512 threads, wave = head, lane = j ----------------
// Bias computed in-loop, slice-parallel: wave h owns d-slice [8h,8h+8); thread reads
// 8 pw values (4 f2) and feeds ALL 8 heads (64 fma), partials reduced via 16KB LDS.
__global__ __launch_bounds__(512, 2) void k_attn(
    const float* __restrict__ pairw,
    const float* __restrict__ rot, const float* __restrict__ trans,
    const float* __restrict__ Wpair, const float* __restrict__ bpair,
    const float* __restrict__ pweights,
    const float* __restrict__ qsg, const float* __restrict__ qpg, const float* __restrict__ qqg,
    const float4* __restrict__ kst, const float4* __restrict__ kpt, const float* __restrict__ kkg,
    const float4* __restrict__ vst, const float4* __restrict__ vpt,
    float* __restrict__ feats)
{
    __shared__ float pwt[JC][PWPAD];      // pairwise tile (16.9KB)
    __shared__ float parts[8][HH][JC];    // [slice][head][j] bias partials (16KB)
    __shared__ float Wl[512];             // W_pair [d][h] row-major
    __shared__ float plds[HH][JC];
    __shared__ float qsh[HH][16];
    __shared__ float qph[HH][12];
    __shared__ float qqh[HH];

    const int t = threadIdx.x;
    const int bi = blockIdx.x;
    const int b = bi >> 9;
    const int h = t >> 6, l = t & 63;  // wave = head, lane = j-in-chunk

    Wl[t] = Wpair[t];

    const int bh = b * HH + h;
    const size_t rowq = (size_t)bh * NN + (bi & 511);
    if (l < 16) qsh[h][l] = qsg[rowq * 16 + l];
    if (l < 12) qph[h][l] = qpg[rowq * 12 + l];
    if (l == 0) qqh[h] = qqg[rowq];

    const float coefP = -0.5f * log1pf(__expf(pweights[h])) * POINT_SCALE;
    const float bp_h = bpair[h];

    const float4* ksb = kst + (size_t)bh * 2048;   // [4][512] f4
    const float4* vsb = vst + (size_t)bh * 2048;
    const float4* kpb = kpt + (size_t)bh * 1536;   // [3][512] f4
    const float4* vpb = vpt + (size_t)bh * 3072;   // [6][512] f4
    const float*  kkb = kkg + (size_t)bh * 512;

    const float4* pwsrc = (const float4*)(pairw + (size_t)bi * NN * PDD);

    float m = -3.0e38f, lsum = 0.f;
    float ap0 = 0.f, ap1 = 0.f, ap2 = 0.f, ap3 = 0.f;
    float ascd[16], aptd[24];
#pragma unroll
    for (int d = 0; d < 16; ++d) ascd[d] = 0.f;
#pragma unroll
    for (int d = 0; d < 24; ++d) aptd[d] = 0.f;

    for (int c = 0; c < NN / JC; ++c) {
        __syncthreads();   // A: prev chunk's pwt/parts reads done
        {   // stage pairwise chunk (f2 LDS writes, min-slot banks)
            const float4* s = pwsrc + (size_t)c * 1024;
            float4 vA = s[t], vB = s[t + 512];
            int jA = t >> 4, dA = (t & 15) * 4;
            *(float2*)&pwt[jA][dA]     = make_float2(vA.x, vA.y);
            *(float2*)&pwt[jA][dA + 2] = make_float2(vA.z, vA.w);
            int f2i = t + 512, jB = f2i >> 4, dB = (f2i & 15) * 4;
            *(float2*)&pwt[jB][dB]     = make_float2(vB.x, vB.y);
            *(float2*)&pwt[jB][dB + 2] = make_float2(vB.z, vB.w);
        }
        __syncthreads();   // B: pwt ready
        {   // bias partials: slice = h, row = l
            float2 u0 = *(const float2*)&pwt[l][8 * h + 0];
            float2 u1 = *(const float2*)&pwt[l][8 * h + 2];
            float2 u2 = *(const float2*)&pwt[l][8 * h + 4];
            float2 u3 = *(const float2*)&pwt[l][8 * h + 6];
            float pv0 = u0.x, pv1 = u0.y, pv2 = u1.x, pv3 = u1.y;
            float pv4 = u2.x, pv5 = u2.y, pv6 = u3.x, pv7 = u3.y;
            float ps[8];
#pragma unroll
            for (int hh = 0; hh < 8; ++hh) ps[hh] = 0.f;
#pragma unroll
            for (int k = 0; k < 8; ++k) {
                float pk = (k == 0) ? pv0 : (k == 1) ? pv1 : (k == 2) ? pv2 : (k == 3) ? pv3
                         : (k == 4) ? pv4 : (k == 5) ? pv5 : (k == 6) ? pv6 : pv7;
                const float4 w0 = *(const float4*)&Wl[(8 * h + k) * 8];
                const float4 w1 = *(const float4*)&Wl[(8 * h + k) * 8 + 4];
                ps[0] = fmaf(pk, w0.x, ps[0]); ps[1] = fmaf(pk, w0.y, ps[1]);
                ps[2] = fmaf(pk, w0.z, ps[2]); ps[3] = fmaf(pk, w0.w, ps[3]);
                ps[4] = fmaf(pk, w1.x, ps[4]); ps[5] = fmaf(pk, w1.y, ps[5]);
                ps[6] = fmaf(pk, w1.z, ps[6]); ps[7] = fmaf(pk, w1.w, ps[7]);
            }
#pragma unroll
            for (int hh = 0; hh < 8; ++hh) parts[h][hh][l] = ps[hh];
        }
        __syncthreads();   // C: partials ready
        float bs = 0.f;
#pragma unroll
        for (int s2 = 0; s2 < 8; ++s2) bs += parts[s2][h][l];
        const float bias = (bs + bp_h) * PAIR_SCALE;
        // ---- logit (f4-packed d-major loads, all stride-1 coalesced) ----
        const int j = c * JC + l;
        float lg;
        {
            const float4 qs0 = *(const float4*)&qsh[h][0];
            const float4 qs1 = *(const float4*)&qsh[h][4];
            const float4 qs2 = *(const float4*)&qsh[h][8];
            const float4 qs3 = *(const float4*)&qsh[h][12];
            float4 k0 = ksb[j], k1 = ksb[512 + j], k2 = ksb[1024 + j], k3 = ksb[1536 + j];
            float d0 = 0.f, d1 = 0.f;
            d0 = fmaf(qs0.x, k0.x, d0); d0 = fmaf(qs0.y, k0.y, d0);
            d0 = fmaf(qs0.z, k0.z, d0); d0 = fmaf(qs0.w, k0.w, d0);
            d1 = fmaf(qs1.x, k1.x, d1); d1 = fmaf(qs1.y, k1.y, d1);
            d1 = fmaf(qs1.z, k1.z, d1); d1 = fmaf(qs1.w, k1.w, d1);
            d0 = fmaf(qs2.x, k2.x, d0); d0 = fmaf(qs2.y, k2.y, d0);
            d0 = fmaf(qs2.z, k2.z, d0); d0 = fmaf(qs2.w, k2.w, d0);
            d1 = fmaf(qs3.x, k3.x, d1); d1 = fmaf(qs3.y, k3.y, d1);
            d1 = fmaf(qs3.z, k3.z, d1); d1 = fmaf(qs3.w, k3.w, d1);
            const float4 qp0 = *(const float4*)&qph[h][0];
            const float4 qp1 = *(const float4*)&qph[h][4];
            const float4 qp2 = *(const float4*)&qph[h][8];
            float4 P0 = kpb[j], P1 = kpb[512 + j], P2 = kpb[1024 + j];
            float e0 = 0.f, e1 = 0.f;
            e0 = fmaf(qp0.x, P0.x, e0); e0 = fmaf(qp0.y, P0.y, e0);
            e0 = fmaf(qp0.z, P0.z, e0); e0 = fmaf(qp0.w, P0.w, e0);
            e1 = fmaf(qp1.x, P1.x, e1); e1 = fmaf(qp1.y, P1.y, e1);
            e1 = fmaf(qp1.z, P1.z, e1); e1 = fmaf(qp1.w, P1.w, e1);
            e0 = fmaf(qp2.x, P2.x, e0); e0 = fmaf(qp2.y, P2.y, e0);
            e0 = fmaf(qp2.z, P2.z, e0); e0 = fmaf(qp2.w, P2.w, e0);
            float dist = qqh[h] + kkb[j] - 2.f * (e0 + e1);
            lg = fmaf(d0 + d1, SCALAR_SCALE, fmaf(coefP, dist, bias));
        }
        // ---- online softmax across the 64-lane wave, defer-rescale (T13) ----
        float cmax = lg;
#pragma unroll
        for (int off = 32; off > 0; off >>= 1) cmax = fmaxf(cmax, __shfl_xor(cmax, off));
        if (cmax > m + 6.f) {          // wave-uniform branch
            const float sc = __expf(m - cmax);
            m = cmax; lsum *= sc;
            ap0 *= sc; ap1 *= sc; ap2 *= sc; ap3 *= sc;
#pragma unroll
            for (int d = 0; d < 16; ++d) ascd[d] *= sc;
#pragma unroll
            for (int d = 0; d < 24; ++d) aptd[d] *= sc;
        }
        const float p = __expf(lg - m);
        float psum = p;
#pragma unroll
        for (int off = 32; off > 0; off >>= 1) psum += __shfl_xor(psum, off);
        lsum += psum;
        plds[h][l] = p;
        // ---- v accumulation (f4-packed coalesced loads) ----
        {
            float4 v0 = vsb[j], v1 = vsb[512 + j], v2 = vsb[1024 + j], v3 = vsb[1536 + j];
            ascd[0]  = fmaf(p, v0.x, ascd[0]);  ascd[1]  = fmaf(p, v0.y, ascd[1]);
            ascd[2]  = fmaf(p, v0.z, ascd[2]);  ascd[3]  = fmaf(p, v0.w, ascd[3]);
            ascd[4]  = fmaf(p, v1.x, ascd[4]);  ascd[5]  = fmaf(p, v1.y, ascd[5]);
            ascd[6]  = fmaf(p, v1.z, ascd[6]);  ascd[7]  = fmaf(p, v1.w, ascd[7]);
            ascd[8]  = fmaf(p, v2.x, ascd[8]);  ascd[9]  = fmaf(p, v2.y, ascd[9]);
            ascd[10] = fmaf(p, v2.z, ascd[10]); ascd[11] = fmaf(p, v2.w, ascd[11]);
            ascd[12] = fmaf(p, v3.x, ascd[12]); ascd[13] = fmaf(p, v3.y, ascd[13]);
            ascd[14] = fmaf(p, v3.z, ascd[14]); ascd[15] = fmaf(p, v3.w, ascd[15]);
#pragma unroll
            for (int g = 0; g < 6; ++g) {
                float4 w = vpb[g * 512 + j];
                aptd[4 * g + 0] = fmaf(p, w.x, aptd[4 * g + 0]);
                aptd[4 * g + 1] = fmaf(p, w.y, aptd[4 * g + 1]);
                aptd[4 * g + 2] = fmaf(p, w.z, aptd[4 * g + 2]);
                aptd[4 * g + 3] = fmaf(p, w.w, aptd[4 * g + 3]);
            }
        }
        // ---- pair accumulation: lane owns dim d=l; col reads 2-way (free); 4 chains ----
#pragma unroll
        for (int u = 0; u < 16; ++u) {
            float4 p4 = *(const float4*)&plds[h][4 * u];
            ap0 = fmaf(p4.x, pwt[4 * u + 0][l], ap0);
            ap1 = fmaf(p4.y, pwt[4 * u + 1][l], ap1);
            ap2 = fmaf(p4.z, pwt[4 * u + 2][l], ap2);
            ap3 = fmaf(p4.w, pwt[4 * u + 3][l], ap3);
        }
    }

    // ---- epilogue: butterfly-reduce j-partials across 64 lanes ----
#pragma unroll
    for (int off = 32; off > 0; off >>= 1) {
#pragma unroll
        for (int d = 0; d < 16; ++d) ascd[d] += __shfl_xor(ascd[d], off);
#pragma unroll
        for (int d = 0; d < 24; ++d) aptd[d] += __shfl_xor(aptd[d], off);
    }
    const float ap = (ap0 + ap1) + (ap2 + ap3);
    const float inv_l = 1.f / lsum;
    float* fb = feats + (size_t)bi * 896;
    if (l < 16) fb[h * 16 + l] = ascd[l] * inv_l;             // m_scalar
    fb[384 + h * 64 + l] = ap * inv_l;                        // m_pair (lane owns d=l)
    const float tr0 = trans[bi * 3 + 0], tr1 = trans[bi * 3 + 1], tr2 = trans[bi * 3 + 2];
    if (l < 24) {
        const int pp = l / 3, r = l - pp * 3;
        const float c0 = aptd[pp * 3 + 0] * inv_l - tr0;
        const float c1 = aptd[pp * 3 + 1] * inv_l - tr1;
        const float c2 = aptd[pp * 3 + 2] * inv_l - tr2;
        const float* Rm = rot + (size_t)bi * 9 + r * 3;       // R[r][c]
        fb[128 + h * 24 + pp * 3 + r] = fmaf(c0, Rm[0], fmaf(c1, Rm[1], c2 * Rm[2]));
    }
    if (l < 8) {
        const float c0 = aptd[l * 3 + 0] * inv_l - tr0;
        const float c1 = aptd[l * 3 + 1] * inv_l - tr1;
        const float c2 = aptd[l * 3 + 2] * inv_l - tr2;
        fb[320 + h * 8 + l] = sqrtf(fmaf(c0, c0, fmaf(c1, c1, fmaf(c2, c2, EPSV))));
    }
}

// ---------------- output projection: 4 tokens, full 384 cols, f2 loads ----------------
__global__ __launch_bounds__(256) void k_out(
    const float* __restrict__ feats, const float* __restrict__ Wout,
    const float* __restrict__ bout, float* __restrict__ out)
{
    __shared__ float fl[4][896];
    const int t = threadIdx.x;
    const int tok0 = blockIdx.x * 4;
    {
        const float4* src = (const float4*)(feats + (size_t)tok0 * 896);
        float4* dst = (float4*)&fl[0][0];
        dst[t] = src[t];
        dst[t + 256] = src[t + 256];
        dst[t + 512] = src[t + 512];
        if (t < 128) dst[t + 768] = src[t + 768];   // 896 float4 total
    }
    __syncthreads();
    const int tok = t >> 6, l = t & 63;
    float2 a0 = make_float2(0.f, 0.f), a1 = a0, a2 = a0;
#pragma unroll 8
    for (int dd = 0; dd < 896; ++dd) {
        float fv = fl[tok][dd];
        const float* wr = Wout + (size_t)dd * 384;
        float2 w0 = *(const float2*)(wr + 2 * l);
        float2 w1 = *(const float2*)(wr + 2 * l + 128);
        float2 w2 = *(const float2*)(wr + 2 * l + 256);
        a0.x = fmaf(fv, w0.x, a0.x); a0.y = fmaf(fv, w0.y, a0.y);
        a1.x = fmaf(fv, w1.x, a1.x); a1.y = fmaf(fv, w1.y, a1.y);
        a2.x = fmaf(fv, w2.x, a2.x); a2.y = fmaf(fv, w2.y, a2.y);
    }
    float* ob = out + (size_t)(tok0 + tok) * 384;
    float2 b0 = *(const float2*)(bout + 2 * l);
    float2 b1 = *(const float2*)(bout + 2 * l + 128);
    float2 b2 = *(const float2*)(bout + 2 * l + 256);
    *(float2*)(ob + 2 * l)       = make_float2(a0.x + b0.x, a0.y + b0.y);
    *(float2*)(ob + 2 * l + 128) = make_float2(a1.x + b1.x, a1.y + b1.y);
    *(float2*)(ob + 2 * l + 256) = make_float2(a2.x + b2.x, a2.y + b2.y);
}

extern "C" void kernel_launch(void* const* d_in, const int* in_sizes, int n_in,
                              void* d_out, int out_size, void* d_ws, size_t ws_size,
                              hipStream_t stream) {
    const float* x        = (const float*)d_in[0];
    const float* pairw    = (const float*)d_in[1];
    const float* rot      = (const float*)d_in[2];
    const float* trans    = (const float*)d_in[3];
    const int*   pos      = (const int*)d_in[4];
    const float* Wq_s     = (const float*)d_in[6];
    const float* Wk_s     = (const float*)d_in[7];
    const float* Wv_s     = (const float*)d_in[8];
    const float* Wq_p     = (const float*)d_in[9];
    const float* Wk_p     = (const float*)d_in[10];
    const float* Wv_p     = (const float*)d_in[11];
    const float* pweights = (const float*)d_in[12];
    const float* Wpair    = (const float*)d_in[13];
    const float* bpair    = (const float*)d_in[14];
    const float* Wout     = (const float*)d_in[15];
    const float* bout     = (const float*)d_in[16];
    float* out = (float*)d_out;

    float* ws = (float*)d_ws;
    float* cos_t = ws;   ws += 4096;
    float* sin_t = ws;   ws += 4096;
    float* qsg = ws;     ws += BB * HH * NN * 16;
    float* qpg = ws;     ws += BB * HH * NN * 12;
    float* qqg = ws;     ws += BB * HH * NN;
    float4* kst = (float4*)ws; ws += BB * HH * NN * 16;   // [bh][4][N] f4
    float* kpt = ws;     ws += BB * HH * NN * 12;         // [bh][3][N] f4
    float* kkg = ws;     ws += BB * HH * NN;
    float4* vst = (float4*)ws; ws += BB * HH * NN * 16;   // [bh][4][N] f4
    float* vpt = ws;     ws += BB * HH * NN * 24;         // [bh][6][N] f4
    float* feats = ws;   ws += BB * NN * 896;

    k_rope<<<2, 256, 0, stream>>>(cos_t, sin_t);
    k_proj<<<(BB * NN) / 8 * 2, 256, 0, stream>>>(x, rot, trans, pos,
        Wq_s, Wk_s, Wv_s, Wq_p, Wk_p, Wv_p, cos_t, sin_t,
        qsg, qpg, qqg, kst, kpt, kkg, vst, vpt);
    k_attn<<<BB * NN, 512, 0, stream>>>(pairw, rot, trans, Wpair, bpair, pweights,
        qsg, qpg, qqg, kst, (const float4*)kpt, kkg, vst, (const float4*)vpt, feats);
    k_out<<<(BB * NN) / 4, 256, 0, stream>>>(feats, Wout, bout, out);

    (void)in_sizes; (void)n_in; (void)out_size; (void)ws_size;
}

// Round 11
// 431.160 us; speedup vs baseline: 1.3157x; 1.0292x over previous
//
#include <hip/hip_runtime.h>
#include <math.h>

#define BB 4
#define NN 512
#define DIMX 384
#define HH 8
#define PDD 64
#define JC 128
#define PWPAD 66   // f2-aligned rows; scalar col reads and f2 row-slices both min-cost banks

static constexpr float EPSV = 1e-8f;
static constexpr float SCALAR_SCALE = 0.14433756729740643f;  // (3*16)^-0.5
static constexpr float POINT_SCALE  = 0.1360827634879543f;   // (3*4*4.5)^-0.5
static constexpr float PAIR_SCALE   = 0.5773502691896258f;   // 3^-0.5

// ---------------- rope table ----------------
__global__ void k_rope(float* __restrict__ cos_t, float* __restrict__ sin_t) {
    int n = blockIdx.x * blockDim.x + threadIdx.x;
    if (n >= NN) return;
#pragma unroll
    for (int i = 0; i < 8; ++i) {
        float invf = powf(10000.0f, -(float)i / 8.0f);
        float f = (float)n * invf;
        cos_t[n * 8 + i] = cosf(f);
        sin_t[n * 8 + i] = sinf(f);
    }
}

// ---------------- projections + transforms (column-half split) ----------------
__global__ __launch_bounds__(256) void k_proj(
    const float* __restrict__ x, const float* __restrict__ rot,
    const float* __restrict__ trans, const int* __restrict__ pos_ids,
    const float* __restrict__ Wq_s, const float* __restrict__ Wk_s, const float* __restrict__ Wv_s,
    const float* __restrict__ Wq_p, const float* __restrict__ Wk_p, const float* __restrict__ Wv_p,
    const float* __restrict__ cos_t, const float* __restrict__ sin_t,
    float* __restrict__ qsg, float* __restrict__ qpg, float* __restrict__ qqg,
    float4* __restrict__ kst, float* __restrict__ kpt, float* __restrict__ kkg,
    float4* __restrict__ vst, float* __restrict__ vpt)
{
    __shared__ float xl[8][DIMX];
    __shared__ float raw[8][384];
    const int t = threadIdx.x;
    const int tile = blockIdx.x >> 1;
    const int half = blockIdx.x & 1;
    const int tok0 = tile * 8;

    {
        const float4* xg = (const float4*)(x + (size_t)tok0 * DIMX);
        float4* xl4 = (float4*)&xl[0][0];
#pragma unroll
        for (int k = 0; k < 3; ++k) xl4[t + 256 * k] = xg[t + 256 * k];
    }
    __syncthreads();

    const int tok = t >> 5, l = t & 31;
    {
        float4 acc[3];
        const float* wb[3];
        int st[3];
#pragma unroll
        for (int m = 0; m < 3; ++m) {
            int f = l + 32 * m + 96 * half;
            const float* w; int out, c;
            if (f < 32)       { w = Wq_s; out = 128; c = 4 * f; }
            else if (f < 64)  { w = Wk_s; out = 128; c = 4 * f - 128; }
            else if (f < 96)  { w = Wv_s; out = 128; c = 4 * f - 256; }
            else if (f < 120) { w = Wq_p; out = 96;  c = 4 * f - 384; }
            else if (f < 144) { w = Wk_p; out = 96;  c = 4 * f - 480; }
            else              { w = Wv_p; out = 192; c = 4 * f - 576; }
            wb[m] = w + c; st[m] = out;
            acc[m] = make_float4(0.f, 0.f, 0.f, 0.f);
        }
        for (int dd = 0; dd < DIMX; ++dd) {
            float xv = xl[tok][dd];
#pragma unroll
            for (int m = 0; m < 3; ++m) {
                float4 wv = *(const float4*)(wb[m] + (size_t)dd * st[m]);
                acc[m].x = fmaf(xv, wv.x, acc[m].x);
                acc[m].y = fmaf(xv, wv.y, acc[m].y);
                acc[m].z = fmaf(xv, wv.z, acc[m].z);
                acc[m].w = fmaf(xv, wv.w, acc[m].w);
            }
        }
#pragma unroll
        for (int m = 0; m < 3; ++m)
            *(float4*)&raw[tok][4 * (l + 32 * m)] = acc[m];
    }
    __syncthreads();

    const int h = l >> 2, q = l & 3;
    const int n_g = tok0 + tok;
    const int b = n_g / NN;
    const int nloc = n_g - b * NN;
    const int bh = b * HH + h;
    const size_t rowi = (size_t)bh * NN + nloc;

    if (half == 0) {
        const int pos = pos_ids[n_g];
        float qv[4], kv[4], vv[4];
#pragma unroll
        for (int dd0 = 0; dd0 < 4; ++dd0) {
            int dd = q * 4 + dd0;
            int i8 = dd & 7;
            float c = cos_t[pos * 8 + i8], s = sin_t[pos * 8 + i8];
            float xq = raw[tok][h * 16 + dd];
            float rq = (dd < 8) ? -raw[tok][h * 16 + dd + 8] : raw[tok][h * 16 + dd - 8];
            qv[dd0] = fmaf(xq, c, rq * s);
            float xk = raw[tok][128 + h * 16 + dd];
            float rk = (dd < 8) ? -raw[tok][128 + h * 16 + dd + 8] : raw[tok][128 + h * 16 + dd - 8];
            kv[dd0] = fmaf(xk, c, rk * s);
            vv[dd0] = raw[tok][256 + h * 16 + dd];
        }
        *(float4*)&qsg[rowi * 16 + q * 4] = make_float4(qv[0], qv[1], qv[2], qv[3]);
        kst[(size_t)bh * 2048 + q * 512 + nloc] = make_float4(kv[0], kv[1], kv[2], kv[3]);
        vst[(size_t)bh * 2048 + q * 512 + nloc] = make_float4(vv[0], vv[1], vv[2], vv[3]);
    } else {
        const float* Rm = rot + (size_t)n_g * 9;
        const float trv[3] = {trans[n_g * 3 + 0], trans[n_g * 3 + 1], trans[n_g * 3 + 2]};
        float qqp = 0.f, kkp = 0.f;
        {
            float pc[3], kc[3];
#pragma unroll
            for (int c = 0; c < 3; ++c) {
                pc[c] = raw[tok][h * 12 + q * 3 + c];
                kc[c] = raw[tok][96 + h * 12 + q * 3 + c];
            }
#pragma unroll
            for (int r = 0; r < 3; ++r) {
                float vq = trv[r], vk = trv[r];
#pragma unroll
                for (int c = 0; c < 3; ++c) {
                    vq = fmaf(pc[c], Rm[c * 3 + r], vq);
                    vk = fmaf(kc[c], Rm[c * 3 + r], vk);
                }
                qpg[rowi * 12 + q * 3 + r] = vq;
                int d = q * 3 + r;   // 0..11
                kpt[(size_t)bh * 6144 + (d >> 2) * 2048 + nloc * 4 + (d & 3)] = vk;
                qqp = fmaf(vq, vq, qqp);
                kkp = fmaf(vk, vk, kkp);
            }
        }
        qqp += __shfl_xor(qqp, 1); qqp += __shfl_xor(qqp, 2);
        kkp += __shfl_xor(kkp, 1); kkp += __shfl_xor(kkp, 2);
        if (q == 0) { qqg[rowi] = qqp; kkg[rowi] = kkp; }
#pragma unroll
        for (int pp = 0; pp < 2; ++pp) {
            int p = q + 4 * pp;
            float pc[3];
#pragma unroll
            for (int c = 0; c < 3; ++c) pc[c] = raw[tok][192 + h * 24 + p * 3 + c];
#pragma unroll
            for (int r = 0; r < 3; ++r) {
                float v = trv[r];
#pragma unroll
                for (int c = 0; c < 3; ++c) v = fmaf(pc[c], Rm[c * 3 + r], v);
                int d = p * 3 + r;   // 0..23
                vpt[(size_t)bh * 12288 + (d >> 2) * 2048 + nloc * 4 + (d & 3)] = v;
            }
        }
    }
}

// ---------------- fused attention: 512 threads, wave = head, lane = j (2 j/lane, JC=128) ----------------
__global__ __launch_bounds__(512, 2) void k_attn(
    const float* __restrict__ pairw,
    const float* __restrict__ rot, const float* __restrict__ trans,
    const float* __restrict__ Wpair, const float* __restrict__ bpair,
    const float* __restrict__ pweights,
    const float* __restrict__ qsg, const float* __restrict__ qpg, const float* __restrict__ qqg,
    const float4* __restrict__ kst, const float4* __restrict__ kpt, const float* __restrict__ kkg,
    const float4* __restrict__ vst, const float4* __restrict__ vpt,
    float* __restrict__ feats)
{
    __shared__ float pwt[JC][PWPAD];      // pairwise tile (33.8KB)
    __shared__ float parts[8][HH][JC];    // [slice][head][j] bias partials (32KB)
    __shared__ float Wl[512];             // W_pair [d][h]
    __shared__ float plds[HH][JC];

    const int t = threadIdx.x;
    const int bi = blockIdx.x;
    const int b = bi >> 9;
    const int h = t >> 6, l = t & 63;

    Wl[t] = Wpair[t];

    const int bh = b * HH + h;
    const size_t rowq = (size_t)bh * NN + (bi & 511);

    // q in registers (r7-proven at (512,2))
    float4 qs0, qs1, qs2, qs3, qp0, qp1, qp2;
    {
        const float4* q4 = (const float4*)(qsg + rowq * 16);
        qs0 = q4[0]; qs1 = q4[1]; qs2 = q4[2]; qs3 = q4[3];
        const float4* p4 = (const float4*)(qpg + rowq * 12);
        qp0 = p4[0]; qp1 = p4[1]; qp2 = p4[2];
    }
    const float qq_r = qqg[rowq];
    const float coefP = -0.5f * log1pf(__expf(pweights[h])) * POINT_SCALE;
    const float bp_h = bpair[h];

    const float4* ksb = kst + (size_t)bh * 2048;   // [4][512] f4
    const float4* vsb = vst + (size_t)bh * 2048;
    const float4* kpb = kpt + (size_t)bh * 1536;   // [3][512] f4
    const float4* vpb = vpt + (size_t)bh * 3072;   // [6][512] f4
    const float*  kkb = kkg + (size_t)bh * 512;

    const float4* pwsrc = (const float4*)(pairw + (size_t)bi * NN * PDD);

    float m = -3.0e38f, lsum = 0.f;
    float ap0 = 0.f, ap1 = 0.f, ap2 = 0.f, ap3 = 0.f;
    float ascd[16], aptd[24];
#pragma unroll
    for (int d = 0; d < 16; ++d) ascd[d] = 0.f;
#pragma unroll
    for (int d = 0; d < 24; ++d) aptd[d] = 0.f;

    for (int c = 0; c < NN / JC; ++c) {
        __syncthreads();   // A: prev chunk's pwt/parts reads done
        {   // stage 128x64 chunk (f2 LDS writes)
            const float4* s = pwsrc + (size_t)c * 2048;
#pragma unroll
            for (int k = 0; k < 4; ++k) {
                int f = t + 512 * k;
                float4 v = s[f];
                int j = f >> 4, d4 = (f & 15) * 4;
                *(float2*)&pwt[j][d4]     = make_float2(v.x, v.y);
                *(float2*)&pwt[j][d4 + 2] = make_float2(v.z, v.w);
            }
        }
        __syncthreads();   // B: pwt ready
        {   // bias partials for j=l and j=l+64, slice = wave h (W reads shared)
            float2 a0 = *(const float2*)&pwt[l][8 * h + 0];
            float2 a1 = *(const float2*)&pwt[l][8 * h + 2];
            float2 a2 = *(const float2*)&pwt[l][8 * h + 4];
            float2 a3 = *(const float2*)&pwt[l][8 * h + 6];
            float2 b0 = *(const float2*)&pwt[l + 64][8 * h + 0];
            float2 b1 = *(const float2*)&pwt[l + 64][8 * h + 2];
            float2 b2 = *(const float2*)&pwt[l + 64][8 * h + 4];
            float2 b3 = *(const float2*)&pwt[l + 64][8 * h + 6];
            float pa[8] = {a0.x, a0.y, a1.x, a1.y, a2.x, a2.y, a3.x, a3.y};
            float pb[8] = {b0.x, b0.y, b1.x, b1.y, b2.x, b2.y, b3.x, b3.y};
            float psA[8], psB[8];
#pragma unroll
            for (int hh = 0; hh < 8; ++hh) { psA[hh] = 0.f; psB[hh] = 0.f; }
#pragma unroll
            for (int k = 0; k < 8; ++k) {
                const float4 w0 = *(const float4*)&Wl[(8 * h + k) * 8];
                const float4 w1 = *(const float4*)&Wl[(8 * h + k) * 8 + 4];
                const float ka = pa[k], kb = pb[k];
                psA[0] = fmaf(ka, w0.x, psA[0]); psA[1] = fmaf(ka, w0.y, psA[1]);
                psA[2] = fmaf(ka, w0.z, psA[2]); psA[3] = fmaf(ka, w0.w, psA[3]);
                psA[4] = fmaf(ka, w1.x, psA[4]); psA[5] = fmaf(ka, w1.y, psA[5]);
                psA[6] = fmaf(ka, w1.z, psA[6]); psA[7] = fmaf(ka, w1.w, psA[7]);
                psB[0] = fmaf(kb, w0.x, psB[0]); psB[1] = fmaf(kb, w0.y, psB[1]);
                psB[2] = fmaf(kb, w0.z, psB[2]); psB[3] = fmaf(kb, w0.w, psB[3]);
                psB[4] = fmaf(kb, w1.x, psB[4]); psB[5] = fmaf(kb, w1.y, psB[5]);
                psB[6] = fmaf(kb, w1.z, psB[6]); psB[7] = fmaf(kb, w1.w, psB[7]);
            }
#pragma unroll
            for (int hh = 0; hh < 8; ++hh) {
                parts[h][hh][l]      = psA[hh];
                parts[h][hh][l + 64] = psB[hh];
            }
        }
        __syncthreads();   // C: partials ready
        float bsA = 0.f, bsB = 0.f;
#pragma unroll
        for (int s2 = 0; s2 < 8; ++s2) { bsA += parts[s2][h][l]; bsB += parts[s2][h][l + 64]; }
        const float bias0 = (bsA + bp_h) * PAIR_SCALE;
        const float bias1 = (bsB + bp_h) * PAIR_SCALE;
        // ---- logits for j0 and j1 ----
        const int j0 = c * JC + l, j1 = j0 + 64;
        float lg0, lg1;
#pragma unroll
        for (int s = 0; s < 2; ++s) {
            const int j = s ? j1 : j0;
            float4 k0 = ksb[j], k1 = ksb[512 + j], k2 = ksb[1024 + j], k3 = ksb[1536 + j];
            float d0 = 0.f, d1 = 0.f;
            d0 = fmaf(qs0.x, k0.x, d0); d0 = fmaf(qs0.y, k0.y, d0);
            d0 = fmaf(qs0.z, k0.z, d0); d0 = fmaf(qs0.w, k0.w, d0);
            d1 = fmaf(qs1.x, k1.x, d1); d1 = fmaf(qs1.y, k1.y, d1);
            d1 = fmaf(qs1.z, k1.z, d1); d1 = fmaf(qs1.w, k1.w, d1);
            d0 = fmaf(qs2.x, k2.x, d0); d0 = fmaf(qs2.y, k2.y, d0);
            d0 = fmaf(qs2.z, k2.z, d0); d0 = fmaf(qs2.w, k2.w, d0);
            d1 = fmaf(qs3.x, k3.x, d1); d1 = fmaf(qs3.y, k3.y, d1);
            d1 = fmaf(qs3.z, k3.z, d1); d1 = fmaf(qs3.w, k3.w, d1);
            float4 P0 = kpb[j], P1 = kpb[512 + j], P2 = kpb[1024 + j];
            float e0 = 0.f, e1 = 0.f;
            e0 = fmaf(qp0.x, P0.x, e0); e0 = fmaf(qp0.y, P0.y, e0);
            e0 = fmaf(qp0.z, P0.z, e0); e0 = fmaf(qp0.w, P0.w, e0);
            e1 = fmaf(qp1.x, P1.x, e1); e1 = fmaf(qp1.y, P1.y, e1);
            e1 = fmaf(qp1.z, P1.z, e1); e1 = fmaf(qp1.w, P1.w, e1);
            e0 = fmaf(qp2.x, P2.x, e0); e0 = fmaf(qp2.y, P2.y, e0);
            e0 = fmaf(qp2.z, P2.z, e0); e0 = fmaf(qp2.w, P2.w, e0);
            float dist = qq_r + kkb[j] - 2.f * (e0 + e1);
            float lg = fmaf(d0 + d1, SCALAR_SCALE, fmaf(coefP, dist, s ? bias1 : bias0));
            if (s) lg1 = lg; else lg0 = lg;
        }
        // ---- online softmax (64-lane wave), defer-rescale (T13) ----
        float cmax = fmaxf(lg0, lg1);
#pragma unroll
        for (int off = 32; off > 0; off >>= 1) cmax = fmaxf(cmax, __shfl_xor(cmax, off));
        if (cmax > m + 6.f) {
            const float sc = __expf(m - cmax);
            m = cmax; lsum *= sc;
            ap0 *= sc; ap1 *= sc; ap2 *= sc; ap3 *= sc;
#pragma unroll
            for (int d = 0; d < 16; ++d) ascd[d] *= sc;
#pragma unroll
            for (int d = 0; d < 24; ++d) aptd[d] *= sc;
        }
        const float p0 = __expf(lg0 - m);
        const float p1 = __expf(lg1 - m);
        float psum = p0 + p1;
#pragma unroll
        for (int off = 32; off > 0; off >>= 1) psum += __shfl_xor(psum, off);
        lsum += psum;
        plds[h][l] = p0;
        plds[h][l + 64] = p1;
        // ---- v accumulation for both j ----
#pragma unroll
        for (int s = 0; s < 2; ++s) {
            const int j = s ? j1 : j0;
            const float p = s ? p1 : p0;
            float4 v0 = vsb[j], v1 = vsb[512 + j], v2 = vsb[1024 + j], v3 = vsb[1536 + j];
            ascd[0]  = fmaf(p, v0.x, ascd[0]);  ascd[1]  = fmaf(p, v0.y, ascd[1]);
            ascd[2]  = fmaf(p, v0.z, ascd[2]);  ascd[3]  = fmaf(p, v0.w, ascd[3]);
            ascd[4]  = fmaf(p, v1.x, ascd[4]);  ascd[5]  = fmaf(p, v1.y, ascd[5]);
            ascd[6]  = fmaf(p, v1.z, ascd[6]);  ascd[7]  = fmaf(p, v1.w, ascd[7]);
            ascd[8]  = fmaf(p, v2.x, ascd[8]);  ascd[9]  = fmaf(p, v2.y, ascd[9]);
            ascd[10] = fmaf(p, v2.z, ascd[10]); ascd[11] = fmaf(p, v2.w, ascd[11]);
            ascd[12] = fmaf(p, v3.x, ascd[12]); ascd[13] = fmaf(p, v3.y, ascd[13]);
            ascd[14] = fmaf(p, v3.z, ascd[14]); ascd[15] = fmaf(p, v3.w, ascd[15]);
#pragma unroll
            for (int g = 0; g < 6; ++g) {
                float4 w = vpb[g * 512 + j];
                aptd[4 * g + 0] = fmaf(p, w.x, aptd[4 * g + 0]);
                aptd[4 * g + 1] = fmaf(p, w.y, aptd[4 * g + 1]);
                aptd[4 * g + 2] = fmaf(p, w.z, aptd[4 * g + 2]);
                aptd[4 * g + 3] = fmaf(p, w.w, aptd[4 * g + 3]);
            }
        }
        // ---- pair accumulation: lane owns dim d=l; 128 col reads (2-way, free) ----
#pragma unroll
        for (int u = 0; u < 32; ++u) {
            float4 p4 = *(const float4*)&plds[h][4 * u];
            ap0 = fmaf(p4.x, pwt[4 * u + 0][l], ap0);
            ap1 = fmaf(p4.y, pwt[4 * u + 1][l], ap1);
            ap2 = fmaf(p4.z, pwt[4 * u + 2][l], ap2);
            ap3 = fmaf(p4.w, pwt[4 * u + 3][l], ap3);
        }
    }

    // ---- epilogue: butterfly-reduce j-partials across 64 lanes ----
#pragma unroll
    for (int off = 32; off > 0; off >>= 1) {
#pragma unroll
        for (int d = 0; d < 16; ++d) ascd[d] += __shfl_xor(ascd[d], off);
#pragma unroll
        for (int d = 0; d < 24; ++d) aptd[d] += __shfl_xor(aptd[d], off);
    }
    const float ap = (ap0 + ap1) + (ap2 + ap3);
    const float inv_l = 1.f / lsum;
    float* fb = feats + (size_t)bi * 896;
    if (l < 16) fb[h * 16 + l] = ascd[l] * inv_l;             // m_scalar
    fb[384 + h * 64 + l] = ap * inv_l;                        // m_pair (lane owns d=l)
    const float tr0 = trans[bi * 3 + 0], tr1 = trans[bi * 3 + 1], tr2 = trans[bi * 3 + 2];
    if (l < 24) {
        const int pp = l / 3, r = l - pp * 3;
        const float c0 = aptd[pp * 3 + 0] * inv_l - tr0;
        const float c1 = aptd[pp * 3 + 1] * inv_l - tr1;
        const float c2 = aptd[pp * 3 + 2] * inv_l - tr2;
        const float* Rm = rot + (size_t)bi * 9 + r * 3;       // R[r][c]
        fb[128 + h * 24 + pp * 3 + r] = fmaf(c0, Rm[0], fmaf(c1, Rm[1], c2 * Rm[2]));
    }
    if (l < 8) {
        const float c0 = aptd[l * 3 + 0] * inv_l - tr0;
        const float c1 = aptd[l * 3 + 1] * inv_l - tr1;
        const float c2 = aptd[l * 3 + 2] * inv_l - tr2;
        fb[320 + h * 8 + l] = sqrtf(fmaf(c0, c0, fmaf(c1, c1, fmaf(c2, c2, EPSV))));
    }
}

// ---------------- output projection: 4 tokens x 192-col half per block (r7-proven) ----------------
__global__ __launch_bounds__(256) void k_out(
    const float* __restrict__ feats, const float* __restrict__ Wout,
    const float* __restrict__ bout, float* __restrict__ out)
{
    __shared__ float fl[4][896];
    const int t = threadIdx.x;
    const int tile = blockIdx.x >> 1;
    const int half = blockIdx.x & 1;
    const int tok0 = tile * 4;
    {
        const float4* src = (const float4*)(feats + (size_t)tok0 * 896);
        float4* dst = (float4*)&fl[0][0];
        dst[t] = src[t];
        dst[t + 256] = src[t + 256];
        dst[t + 512] = src[t + 512];
        if (t < 128) dst[t + 768] = src[t + 768];   // 896 float4 total
    }
    __syncthreads();
    const int tok = t >> 6, l = t & 63;
    const int c0 = 192 * half;
    float acc0 = 0.f, acc1 = 0.f, acc2 = 0.f;
#pragma unroll 8
    for (int dd = 0; dd < 896; ++dd) {
        float fv = fl[tok][dd];
        const float* wr = Wout + (size_t)dd * 384 + c0;
        acc0 = fmaf(fv, wr[l], acc0);
        acc1 = fmaf(fv, wr[l + 64], acc1);
        acc2 = fmaf(fv, wr[l + 128], acc2);
    }
    float* ob = out + (size_t)(tok0 + tok) * 384 + c0;
    ob[l]       = acc0 + bout[c0 + l];
    ob[l + 64]  = acc1 + bout[c0 + l + 64];
    ob[l + 128] = acc2 + bout[c0 + l + 128];
}

extern "C" void kernel_launch(void* const* d_in, const int* in_sizes, int n_in,
                              void* d_out, int out_size, void* d_ws, size_t ws_size,
                              hipStream_t stream) {
    const float* x        = (const float*)d_in[0];
    const float* pairw    = (const float*)d_in[1];
    const float* rot      = (const float*)d_in[2];
    const float* trans    = (const float*)d_in[3];
    const int*   pos      = (const int*)d_in[4];
    const float* Wq_s     = (const float*)d_in[6];
    const float* Wk_s     = (const float*)d_in[7];
    const float* Wv_s     = (const float*)d_in[8];
    const float* Wq_p     = (const float*)d_in[9];
    const float* Wk_p     = (const float*)d_in[10];
    const float* Wv_p     = (const float*)d_in[11];
    const float* pweights = (const float*)d_in[12];
    const float* Wpair    = (const float*)d_in[13];
    const float* bpair    = (const float*)d_in[14];
    const float* Wout     = (const float*)d_in[15];
    const float* bout     = (const float*)d_in[16];
    float* out = (float*)d_out;

    float* ws = (float*)d_ws;
    float* cos_t = ws;   ws += 4096;
    float* sin_t = ws;   ws += 4096;
    float* qsg = ws;     ws += BB * HH * NN * 16;
    float* qpg = ws;     ws += BB * HH * NN * 12;
    float* qqg = ws;     ws += BB * HH * NN;
    float4* kst = (float4*)ws; ws += BB * HH * NN * 16;   // [bh][4][N] f4
    float* kpt = ws;     ws += BB * HH * NN * 12;         // [bh][3][N] f4
    float* kkg = ws;     ws += BB * HH * NN;
    float4* vst = (float4*)ws; ws += BB * HH * NN * 16;   // [bh][4][N] f4
    float* vpt = ws;     ws += BB * HH * NN * 24;         // [bh][6][N] f4
    float* feats = ws;   ws += BB * NN * 896;

    k_rope<<<2, 256, 0, stream>>>(cos_t, sin_t);
    k_proj<<<(BB * NN) / 8 * 2, 256, 0, stream>>>(x, rot, trans, pos,
        Wq_s, Wk_s, Wv_s, Wq_p, Wk_p, Wv_p, cos_t, sin_t,
        qsg, qpg, qqg, kst, kpt, kkg, vst, vpt);
    k_attn<<<BB * NN, 512, 0, stream>>>(pairw, rot, trans, Wpair, bpair, pweights,
        qsg, qpg, qqg, kst, (const float4*)kpt, kkg, vst, (const float4*)vpt, feats);
    k_out<<<(BB * NN) / 4 * 2, 256, 0, stream>>>(feats, Wout, bout, out);

    (void)in_sizes; (void)n_in; (void)out_size; (void)ws_size;
}